// Round 10
// baseline (379.491 us; speedup 1.0000x reference)
//
#include <hip/hip_runtime.h>
#include <hip/hip_bf16.h>
#include <math.h>

#define B_ 2
#define T_ 2048
#define D_ 1024
#define H_ 16
#define DH_ 64
#define M_ (B_*T_)   // 4096 rows
#define NC_ 32       // chunks per sequence (T/64)
#define CS_ 64       // chunk size
#define NCH_ (B_*H_*NC_)  // 1024 chunk-heads
#define QKVN_ 3072   // fused QKV gemm N

typedef __attribute__((ext_vector_type(4))) float floatx4;
typedef __attribute__((ext_vector_type(8))) short short8;

__device__ __forceinline__ ushort f2bf(float f) {
  union { float f; unsigned u; } c; c.f = f;
  unsigned r = (c.u + 0x7FFFu + ((c.u >> 16) & 1u)) >> 16;  // RNE
  return (ushort)r;
}
__device__ __forceinline__ float siluf(float u) {
  return u / (1.f + __expf(-u));
}
__device__ __forceinline__ float f4get(const float4& v, int j) {
  return j == 0 ? v.x : j == 1 ? v.y : j == 2 ? v.z : v.w;
}
__device__ __forceinline__ float rdlane(float v, int l) {
  return __int_as_float(__builtin_amdgcn_readlane(__float_as_int(v), l));
}
// swizzled chunk index for K tiles: chunk c (0..15) of row r stored at c ^ (r>>4)
__device__ __forceinline__ int ksw(int r, int c) { return ((c ^ (r >> 4)) << 2); }

// ---------- cast f32 -> bf16, n4 = n/4 ----------
__global__ void cast_kernel(const float* __restrict__ in, ushort* __restrict__ out, int n4) {
  int i = blockIdx.x * blockDim.x + threadIdx.x;
  if (i >= n4) return;
  float4 v = ((const float4*)in)[i];
  ushort4 o;
  o.x = f2bf(v.x); o.y = f2bf(v.y); o.z = f2bf(v.z); o.w = f2bf(v.w);
  ((ushort4*)out)[i] = o;
}

// ---------- transpose + cast: W[K][N] f32 -> Wt[N][K] bf16 ----------
__global__ void transpose_cast_kernel(const float* __restrict__ W, ushort* __restrict__ Wt,
                                      int K, int N) {
  __shared__ float tile[32][33];
  int tx = threadIdx.x, ty = threadIdx.y;
  int n0 = blockIdx.x * 32, k0 = blockIdx.y * 32;
  #pragma unroll
  for (int i = 0; i < 32; i += 8)
    tile[ty + i][tx] = W[(size_t)(k0 + ty + i) * N + n0 + tx];
  __syncthreads();
  #pragma unroll
  for (int i = 0; i < 32; i += 8)
    Wt[(size_t)(n0 + ty + i) * K + k0 + tx] = f2bf(tile[tx][ty + i]);
}

// ---------- transpose Wb[1024][16] -> WbT[16][1024] (fp32) ----------
__global__ void transpose_wb_kernel(const float* __restrict__ Wb, float* __restrict__ WbT) {
  int bk = blockIdx.x;
  int tid = threadIdx.x;
  int kl = tid >> 4, h = tid & 15;
  int k = bk * 16 + kl;
  WbT[(size_t)h * D_ + k] = Wb[(size_t)k * H_ + h];
}

// ---------- bf16 MFMA GEMM, 2-phase counted-vmcnt pipeline + XCD supertile swizzle ----------
__global__ __launch_bounds__(256) void gemm128_kernel(
    const ushort* __restrict__ A, const ushort* __restrict__ Bt,
    float* __restrict__ C, int M, int N, int K) {
  __shared__ ushort lA[2][128 * 32];
  __shared__ ushort lB[2][128 * 32];
  int tid = threadIdx.x;
  int wave = tid >> 6, lane = tid & 63;
  int wm = wave >> 1, wn = wave & 1;
  int m16 = lane & 15, q4 = lane >> 4;
  // XCD-aware bijective swizzle with 8x8 supertiles
  int nbm = gridDim.x, nbn = gridDim.y;
  int lin = blockIdx.y * nbm + blockIdx.x;
  int cpx = (nbm * nbn) >> 3;
  int swz = (lin & 7) * cpx + (lin >> 3);
  int stn = nbn >> 3;
  int st = swz >> 6, in_ = swz & 63;
  int stm = st / stn, soff = st - stm * stn;
  int bm = stm * 8 + (in_ & 7);
  int bn = soff * 8 + (in_ >> 3);
  floatx4 acc[4][4] = {};
  int srow = tid >> 2;
  int sk8 = tid & 3;
  const ushort* Ag = A + (size_t)(bm * 128 + srow) * K + sk8 * 8;
  const ushort* Bg = Bt + (size_t)(bn * 128 + srow) * K + sk8 * 8;
  int nks = K >> 5;

#define GSTAGE(bufi, kk0)                                                       \
  {                                                                             \
    __builtin_amdgcn_global_load_lds(                                           \
        (const __attribute__((address_space(1))) void*)(Ag + (kk0)),            \
        (__attribute__((address_space(3))) void*)&lA[bufi][tid * 8], 16, 0, 0); \
    __builtin_amdgcn_global_load_lds(                                           \
        (const __attribute__((address_space(1))) void*)(Ag + (size_t)64 * K + (kk0)), \
        (__attribute__((address_space(3))) void*)&lA[bufi][tid * 8 + 2048], 16, 0, 0); \
    __builtin_amdgcn_global_load_lds(                                           \
        (const __attribute__((address_space(1))) void*)(Bg + (kk0)),            \
        (__attribute__((address_space(3))) void*)&lB[bufi][tid * 8], 16, 0, 0); \
    __builtin_amdgcn_global_load_lds(                                           \
        (const __attribute__((address_space(1))) void*)(Bg + (size_t)64 * K + (kk0)), \
        (__attribute__((address_space(3))) void*)&lB[bufi][tid * 8 + 2048], 16, 0, 0); \
  }

  GSTAGE(0, 0);
  int cur = 0;
  #pragma unroll 1
  for (int ks = 0; ks < nks; ++ks) {
    if (ks + 1 < nks) {
      GSTAGE(cur ^ 1, (ks + 1) * 32);
      asm volatile("s_waitcnt vmcnt(4)" ::: "memory");
    } else {
      asm volatile("s_waitcnt vmcnt(0)" ::: "memory");
    }
    __builtin_amdgcn_s_barrier();       // buf[cur] staged & visible
    __builtin_amdgcn_sched_barrier(0);
    short8 af[4], bf[4];
    #pragma unroll
    for (int i = 0; i < 4; i++) {
      af[i] = *(short8*)&lA[cur][(wm * 64 + i * 16 + m16) * 32 + q4 * 8];
      bf[i] = *(short8*)&lB[cur][(wn * 64 + i * 16 + m16) * 32 + q4 * 8];
    }
    #pragma unroll
    for (int mi = 0; mi < 4; mi++)
      #pragma unroll
      for (int nj = 0; nj < 4; nj++)
        acc[mi][nj] = __builtin_amdgcn_mfma_f32_16x16x32_bf16(af[mi], bf[nj], acc[mi][nj], 0, 0, 0);
    __builtin_amdgcn_s_barrier();       // all waves done reading buf[cur]
    cur ^= 1;
  }
#undef GSTAGE
  float* Cb = C + (size_t)(bm * 128) * N + bn * 128;
  #pragma unroll
  for (int mi = 0; mi < 4; mi++) {
    #pragma unroll
    for (int nj = 0; nj < 4; nj++) {
      #pragma unroll
      for (int i = 0; i < 4; i++) {
        int row = wm * 64 + mi * 16 + q4 * 4 + i;
        int col = wn * 64 + nj * 16 + m16;
        Cb[(size_t)row * N + col] = acc[mi][nj][i];
      }
    }
  }
}

// ---------- beta = sigmoid(x @ Wb), WbT[16][1024], conflict-free ----------
__global__ __launch_bounds__(256) void beta_kernel(const float* __restrict__ x,
                                                   const float* __restrict__ WbT,
                                                   float* __restrict__ beta) {
  __shared__ __align__(16) float xs[D_];
  int row = blockIdx.x;
  int tid = threadIdx.x;
  ((float4*)xs)[tid] = ((const float4*)(x + (size_t)row * D_))[tid];
  __syncthreads();
  int h = tid >> 4;
  int seg = tid & 15;
  const float4* wrow = (const float4*)(WbT + (size_t)h * D_) + seg * 16;
  const float4* xsrow = (const float4*)xs + seg * 16;
  float s = 0.f;
  #pragma unroll
  for (int j = 0; j < 16; j++) {
    int jj = (j + seg) & 15;
    float4 xv = xsrow[jj];
    float4 wv = wrow[jj];
    s += xv.x * wv.x + xv.y * wv.y + xv.z * wv.z + xv.w * wv.w;
  }
  #pragma unroll
  for (int off = 8; off; off >>= 1) s += __shfl_down(s, off, 16);
  if (seg == 0) beta[(size_t)row * H_ + h] = 1.f / (1.f + __expf(-s));
}

// ---------- causal depthwise conv(K=4) + silu, l2norm for q,k ----------
__global__ __launch_bounds__(256) void conv_kernel(
    const float* __restrict__ qkv,
    const float* __restrict__ cq, const float* __restrict__ ck, const float* __restrict__ cv,
    float* __restrict__ qo, float* __restrict__ ko, float* __restrict__ vo) {
  int row = blockIdx.x;
  int t = row & (T_ - 1);
  int tid = threadIdx.x;
  int c0 = tid * 4;
  float4 zf = {0.f, 0.f, 0.f, 0.f};
  float4 xq[4], xk[4], xv[4];
  #pragma unroll
  for (int i = 0; i < 4; i++) {
    int tt = t - 3 + i;
    if (tt >= 0) {
      const float* rp = qkv + (size_t)(row - 3 + i) * QKVN_;
      xq[i] = *(const float4*)(rp + c0);
      xk[i] = *(const float4*)(rp + 1024 + c0);
      xv[i] = *(const float4*)(rp + 2048 + c0);
    } else { xq[i] = zf; xk[i] = zf; xv[i] = zf; }
  }
  float yq[4], yk[4], yv[4];
  float pq = 0.f, pk = 0.f;
  #pragma unroll
  for (int j = 0; j < 4; j++) {
    float4 wq = ((const float4*)cq)[c0 + j];
    float4 wk = ((const float4*)ck)[c0 + j];
    float4 wv = ((const float4*)cv)[c0 + j];
    float sq = 0.f, sk = 0.f, sv = 0.f;
    #pragma unroll
    for (int i = 0; i < 4; i++) {
      sq += f4get(wq, i) * f4get(xq[i], j);
      sk += f4get(wk, i) * f4get(xk[i], j);
      sv += f4get(wv, i) * f4get(xv[i], j);
    }
    yq[j] = siluf(sq); yk[j] = siluf(sk); yv[j] = siluf(sv);
    pq += yq[j] * yq[j]; pk += yk[j] * yk[j];
  }
  #pragma unroll
  for (int off = 1; off < 16; off <<= 1) {
    pq += __shfl_xor(pq, off, 16);
    pk += __shfl_xor(pk, off, 16);
  }
  float rq = rsqrtf(pq + 1e-6f), rk = rsqrtf(pk + 1e-6f);
  float4 oq = {yq[0]*rq, yq[1]*rq, yq[2]*rq, yq[3]*rq};
  float4 okk = {yk[0]*rk, yk[1]*rk, yk[2]*rk, yk[3]*rk};
  float4 ov = {yv[0], yv[1], yv[2], yv[3]};
  *(float4*)(qo + (size_t)row * D_ + c0) = oq;
  *(float4*)(ko + (size_t)row * D_ + c0) = okk;
  *(float4*)(vo + (size_t)row * D_ + c0) = ov;
}

// ================= chunked delta rule =================
// prep1: A = strict_tril(diag(b)KK^T); solve (I+A)Wk = diag(b)K and (I+A)U0 = diag(b)V
// A-phase via split-bf16 MFMA. hi/lo split happens IN the staging loop (load kn
// fp32 -> split 8 values in registers -> ds_write to bank-staggered KH/KL).
// One-time ~100 VALU/thread (not R4's per-use 400). LDS layout: row stride 160B,
// XOR-16 swizzle applied identically on write-col and read-col (involution).
// A = hh + hl + lh MFMAs (error ~2^-23 rel). Solve phases unchanged (R3-verified).
__global__ __launch_bounds__(256) void prep1_kernel(
    const float* __restrict__ kn, const float* __restrict__ vn,
    const float* __restrict__ beta,
    float* __restrict__ Wkbuf, float* __restrict__ U0buf) {
  __shared__ __align__(16) float Ash[64 * 68];   // A[t][s] row-major, stride 68
  __shared__ float bsh[64];
  // union region: KH/KL (during A compute) aliased with Tsh/Msh/Xsh (after)
  __shared__ __align__(16) float uni[5312];
  ushort* KH = (ushort*)uni;                                // 64 rows x 160B = 10240B
  ushort* KL = (ushort*)uni + 5120;                         // next 10240B
  float (*Tsh)[16][20] = (float (*)[16][20])uni;            // [4][16][20] = 1280
  float (*Msh)[16][20] = (float (*)[16][20])(uni + 1280);   // [6][16][20] = 1920
  float (*Xsh)[132] = (float (*)[132])(uni + 3200);         // [16][132]  = 2112

  int ch = blockIdx.x;
  int b = ch >> 9, h = (ch >> 5) & 15, c = ch & 31;
  int tid = threadIdx.x;
  int t = tid >> 2, seg = tid & 3;
  int wave = tid >> 6, lane = tid & 63;
  int r = lane >> 2, q = lane & 3;   // r == t&15, q == seg
  int m16 = lane & 15, oct = lane >> 4;
  const float* kg = kn + ((size_t)(b * T_ + c * 64)) * D_ + h * 64;
  // stage KH/KL: 2 passes x 256 threads x (8 bf16 = 16B dest); load fp32 from kn,
  // split hi/lo in registers, write to swizzled column (involution with read).
  {
    #pragma unroll
    for (int p = 0; p < 2; p++) {
      int idx = p * 256 + tid;          // 16B dest unit
      int row = idx >> 3, cb = (idx & 7) * 16;
      int scb = cb ^ ((row & 7) << 4);  // source byte col (bf16 units)
      const float* src = kg + (size_t)row * D_ + (scb >> 1);
      float4 va = *(const float4*)src;
      float4 vb = *(const float4*)(src + 4);
      float v[8] = {va.x, va.y, va.z, va.w, vb.x, vb.y, vb.z, vb.w};
      short8 hi8, lo8;
      #pragma unroll
      for (int j = 0; j < 8; j++) {
        unsigned u = __float_as_uint(v[j]);
        hi8[j] = (short)(u >> 16);                      // truncated bf16 hi
        lo8[j] = (short)f2bf(v[j] - __uint_as_float(u & 0xFFFF0000u));
      }
      *(short8*)((char*)KH + row * 160 + cb) = hi8;
      *(short8*)((char*)KL + row * 160 + cb) = lo8;
    }
  }
  if (tid < 64) bsh[tid] = beta[((size_t)(b * T_ + c * 64 + tid)) * H_ + h];
  __syncthreads();
  // A[t][s] = (t>s) ? b_t * (k_t . k_s) : 0 — split-bf16 MFMA; wave w owns row-tile w
  {
    floatx4 acc[4] = {};
    #pragma unroll
    for (int ks = 0; ks < 2; ks++) {
      int ob = (ks * 64 + oct * 16) ^ ((m16 & 7) << 4);
      short8 fah = *(short8*)((char*)KH + (wave * 16 + m16) * 160 + ob);
      short8 fal = *(short8*)((char*)KL + (wave * 16 + m16) * 160 + ob);
      #pragma unroll
      for (int si = 0; si < 4; si++) {
        short8 fbh = *(short8*)((char*)KH + (si * 16 + m16) * 160 + ob);
        short8 fbl = *(short8*)((char*)KL + (si * 16 + m16) * 160 + ob);
        acc[si] = __builtin_amdgcn_mfma_f32_16x16x32_bf16(fah, fbh, acc[si], 0, 0, 0);
        acc[si] = __builtin_amdgcn_mfma_f32_16x16x32_bf16(fah, fbl, acc[si], 0, 0, 0);
        acc[si] = __builtin_amdgcn_mfma_f32_16x16x32_bf16(fal, fbh, acc[si], 0, 0, 0);
      }
    }
    // D layout: row-in-tile = oct*4+rr, col = m16 (verified C/D mapping)
    #pragma unroll
    for (int si = 0; si < 4; si++) {
      #pragma unroll
      for (int rr = 0; rr < 4; rr++) {
        int row = wave * 16 + oct * 4 + rr;
        int col = si * 16 + m16;
        float bt = bsh[row];
        Ash[row * 68 + col] = (row > col) ? bt * acc[si][rr] : 0.f;
      }
    }
  }
  // RHS (residual Y) in registers: row t, 16 K-cols + 16 V-cols (fp32 from global)
  float xk[16], xv[16];
  {
    float bt = bsh[t];
    const float* krow = kn + ((size_t)(b * T_ + c * 64 + t)) * D_ + h * 64;
    const float* vrow = vn + ((size_t)(b * T_ + c * 64 + t)) * D_ + h * 64;
    #pragma unroll
    for (int g = 0; g < 4; g++) {
      float4 kv = *(const float4*)&krow[seg * 16 + 4 * g];
      float4 vv = *(const float4*)&vrow[seg * 16 + 4 * g];
      xk[4*g+0] = bt * kv.x; xk[4*g+1] = bt * kv.y; xk[4*g+2] = bt * kv.z; xk[4*g+3] = bt * kv.w;
      xv[4*g+0] = bt * vv.x; xv[4*g+1] = bt * vv.y; xv[4*g+2] = bt * vv.z; xv[4*g+3] = bt * vv.w;
    }
  }
  __syncthreads();   // Ash ready; KH/KL dead -> Tsh/Msh/Xsh region live
  // Phase A: wave-parallel 16x16 diagonal-block inverse via fwd substitution on I
  {
    float a[16];
    #pragma unroll
    for (int i = 0; i < 16; i++) a[i] = Ash[(wave * 16 + r) * 68 + wave * 16 + i];
    float4 w4 = {0.f, 0.f, 0.f, 0.f};
    if ((r >> 2) == q) ((float*)&w4)[r & 3] = 1.f;
    #pragma unroll
    for (int i = 0; i < 15; i++) {
      int src = i * 4 + q;
      float4 wi;
      wi.x = __shfl(w4.x, src, 64);
      wi.y = __shfl(w4.y, src, 64);
      wi.z = __shfl(w4.z, src, 64);
      wi.w = __shfl(w4.w, src, 64);
      if (r > i) {
        w4.x -= a[i] * wi.x; w4.y -= a[i] * wi.y;
        w4.z -= a[i] * wi.z; w4.w -= a[i] * wi.w;
      }
    }
    *(float4*)&Tsh[wave][r][q * 4] = w4;
  }
  __syncthreads();   // Tsh visible to all waves
  // Phase B: M_wk = A_wk * T_kk (wave-local write, wave-local read)
  for (int k = 0; k < wave; k++) {
    float4 m4 = {0.f, 0.f, 0.f, 0.f};
    #pragma unroll
    for (int i = 0; i < 16; i++) {
      float aik = Ash[(wave * 16 + r) * 68 + k * 16 + i];
      float4 tk = *(float4*)&Tsh[k][i][q * 4];
      m4.x += aik * tk.x; m4.y += aik * tk.y;
      m4.z += aik * tk.z; m4.w += aik * tk.w;
    }
    int mi = wave * (wave - 1) / 2 + k;
    *(float4*)&Msh[mi][r][q * 4] = m4;
  }
  // Block substitution k-loop
  float* wkout = &Wkbuf[(size_t)ch * 4096 + t * 64];
  float* u0out = &U0buf[(size_t)ch * 4096 + t * 64];
  for (int k = 0; k < 4; k++) {
    if (wave == k) {   // publish residual Y_k
      #pragma unroll
      for (int g = 0; g < 4; g++) {
        float4 k4 = {xk[4*g+0], xk[4*g+1], xk[4*g+2], xk[4*g+3]};
        float4 v4 = {xv[4*g+0], xv[4*g+1], xv[4*g+2], xv[4*g+3]};
        *(float4*)&Xsh[r][seg * 16 + 4 * g] = k4;
        *(float4*)&Xsh[r][64 + seg * 16 + 4 * g] = v4;
      }
    }
    __syncthreads();
    if (wave == k) {
      // X_k = T_kk * Y_k -> final output, straight to global
      float nk[16], nv[16];
      #pragma unroll
      for (int i2 = 0; i2 < 16; i2++) { nk[i2] = 0.f; nv[i2] = 0.f; }
      #pragma unroll
      for (int i = 0; i < 16; i++) {
        float tc = Tsh[k][r][i];
        #pragma unroll
        for (int g = 0; g < 4; g++) {
          float4 yk = *(float4*)&Xsh[i][seg * 16 + 4 * g];
          float4 yv = *(float4*)&Xsh[i][64 + seg * 16 + 4 * g];
          nk[4*g+0] += tc * yk.x; nk[4*g+1] += tc * yk.y;
          nk[4*g+2] += tc * yk.z; nk[4*g+3] += tc * yk.w;
          nv[4*g+0] += tc * yv.x; nv[4*g+1] += tc * yv.y;
          nv[4*g+2] += tc * yv.z; nv[4*g+3] += tc * yv.w;
        }
      }
      #pragma unroll
      for (int g = 0; g < 4; g++) {
        float4 k4 = {nk[4*g+0], nk[4*g+1], nk[4*g+2], nk[4*g+3]};
        float4 v4 = {nv[4*g+0], nv[4*g+1], nv[4*g+2], nv[4*g+3]};
        *(float4*)&wkout[seg * 16 + 4 * g] = k4;
        *(float4*)&u0out[seg * 16 + 4 * g] = v4;
      }
    } else if (wave > k) {
      // Y_i -= M_ik * Y_k   (== A_ik * X_k)
      int mi = wave * (wave - 1) / 2 + k;
      #pragma unroll
      for (int i = 0; i < 16; i++) {
        float mc = Msh[mi][r][i];
        #pragma unroll
        for (int g = 0; g < 4; g++) {
          float4 yk = *(float4*)&Xsh[i][seg * 16 + 4 * g];
          float4 yv = *(float4*)&Xsh[i][64 + seg * 16 + 4 * g];
          xk[4*g+0] -= mc * yk.x; xk[4*g+1] -= mc * yk.y;
          xk[4*g+2] -= mc * yk.z; xk[4*g+3] -= mc * yk.w;
          xv[4*g+0] -= mc * yv.x; xv[4*g+1] -= mc * yv.y;
          xv[4*g+2] -= mc * yv.z; xv[4*g+3] -= mc * yv.w;
        }
      }
    }
    __syncthreads();
  }
}

// prep2ab: fused prep2a+prep2b. Phase 1: L = tril(Q K^T) -> Lsh (LDS, no HBM
// roundtrip), with 4x4 register output tiling (8 float4 reads / 64 FMAs per d4).
// Phase 2: reuse Qsh/Ksh LDS space for Wk/U0 staging, then
// O0 = L U0 ; Qeff = Q - L Wk (identical arithmetic order to the old kernels).
__global__ __launch_bounds__(256) void prep2ab_kernel(
    float* qn, const float* __restrict__ kn,
    const float* __restrict__ Wkbuf, const float* __restrict__ U0buf,
    float* __restrict__ O0buf) {
  __shared__ float Qsh[64][68];   // phase 2: Wksh
  __shared__ float Ksh[64][68];   // swizzled; phase 2: U0sh
  __shared__ float Lsh[64][68];
  float (*Wksh)[68] = Qsh;
  float (*U0sh)[68] = Ksh;
  int ch = blockIdx.x;
  int b = ch >> 9, h = (ch >> 5) & 15, c = ch & 31;
  int tid = threadIdx.x;
  int t = tid >> 2, seg = tid & 3;
  const float* qrow = qn + ((size_t)(b * T_ + c * 64 + t)) * D_ + h * 64;
  const float* krow = kn + ((size_t)(b * T_ + c * 64 + t)) * D_ + h * 64;
  #pragma unroll
  for (int g = 0; g < 4; g++) {
    *(float4*)&Qsh[t][seg * 16 + 4 * g] = *(const float4*)&qrow[seg * 16 + 4 * g];
    *(float4*)&Ksh[t][ksw(t, seg * 4 + g)] = *(const float4*)&krow[seg * 16 + 4 * g];
  }
  __syncthreads();
  // phase 1: L = tril(Q K^T) -> Lsh, 4x4 register tile per thread
  {
    int qt = tid >> 4, qs = tid & 15;
    int sws = qs >> 2;
    float acc[4][4];
    #pragma unroll
    for (int i = 0; i < 4; i++)
      #pragma unroll
      for (int j = 0; j < 4; j++) acc[i][j] = 0.f;
    for (int d4 = 0; d4 < 16; d4++) {
      float4 qv[4], ks[4];
      #pragma unroll
      for (int i = 0; i < 4; i++) qv[i] = *(float4*)&Qsh[qt * 4 + i][d4 * 4];
      #pragma unroll
      for (int j = 0; j < 4; j++) ks[j] = *(float4*)&Ksh[qs * 4 + j][((d4 ^ sws) << 2)];
      #pragma unroll
      for (int i = 0; i < 4; i++)
        #pragma unroll
        for (int j = 0; j < 4; j++)
          acc[i][j] += qv[i].x * ks[j].x + qv[i].y * ks[j].y
                     + qv[i].z * ks[j].z + qv[i].w * ks[j].w;
    }
    #pragma unroll
    for (int i = 0; i < 4; i++) {
      int row = qt * 4 + i;
      float4 ov;
      ov.x = (qs * 4 + 0 <= row) ? acc[i][0] : 0.f;
      ov.y = (qs * 4 + 1 <= row) ? acc[i][1] : 0.f;
      ov.z = (qs * 4 + 2 <= row) ? acc[i][2] : 0.f;
      ov.w = (qs * 4 + 3 <= row) ? acc[i][3] : 0.f;
      *(float4*)&Lsh[row][qs * 4] = ov;
    }
  }
  __syncthreads();   // L done; Qsh/Ksh dead -> stage Wk/U0 into their space
  #pragma unroll
  for (int g = 0; g < 4; g++) {
    int o = t * 64 + seg * 16 + 4 * g;
    *(float4*)&Wksh[t][seg * 16 + 4 * g] = *(const float4*)&Wkbuf[(size_t)ch * 4096 + o];
    *(float4*)&U0sh[t][seg * 16 + 4 * g] = *(const float4*)&U0buf[(size_t)ch * 4096 + o];
  }
  __syncthreads();
  // phase 2: O0 = L U0 ; Qeff = Q - L Wk (identical to old prep2b)
  int j0 = seg * 16;
  float o0[16], lw[16];
  #pragma unroll
  for (int r = 0; r < 16; r++) { o0[r] = 0.f; lw[r] = 0.f; }
  for (int s = 0; s <= t; s++) {
    float l = Lsh[t][s];
    #pragma unroll
    for (int g = 0; g < 4; g++) {
      float4 u = *(float4*)&U0sh[s][j0 + 4 * g];
      float4 w = *(float4*)&Wksh[s][j0 + 4 * g];
      o0[4*g+0] += l * u.x; o0[4*g+1] += l * u.y; o0[4*g+2] += l * u.z; o0[4*g+3] += l * u.w;
      lw[4*g+0] += l * w.x; lw[4*g+1] += l * w.y; lw[4*g+2] += l * w.z; lw[4*g+3] += l * w.w;
    }
  }
  float* qwrow = qn + ((size_t)(b * T_ + c * 64 + t)) * D_ + h * 64;
  #pragma unroll
  for (int g = 0; g < 4; g++) {
    float4 qv = *(const float4*)&qwrow[j0 + 4 * g];
    qv.x -= lw[4*g+0]; qv.y -= lw[4*g+1]; qv.z -= lw[4*g+2]; qv.w -= lw[4*g+3];
    *(float4*)&qwrow[j0 + 4 * g] = qv;
    float4 ov = {o0[4*g+0], o0[4*g+1], o0[4*g+2], o0[4*g+3]};
    *(float4*)&O0buf[(size_t)ch * 4096 + t * 64 + j0 + 4 * g] = ov;
  }
}

// prep2c: P[d][e] = I - (K^T Wk)[d][e], stored SLOT-MAJOR for state_kernel:
//         float4 #(f*64+d) of chunk = P[d][4f..4f+3]  (so a wave reading slot f,
//         all rows d, is one contiguous 1KB block).
//         Zt[j][d] = (U0^T K)[j][d] -> kn rows j (coalesced), unchanged.
__global__ __launch_bounds__(256) void prep2c_kernel(
    float* kn, const float* __restrict__ Wkbuf,
    const float* __restrict__ U0buf, float* __restrict__ Pbuf) {
  __shared__ float Ksh[64][68];
  __shared__ float Wksh[64][68];
  __shared__ float U0sh[64][68];
  int ch = blockIdx.x;
  int b = ch >> 9, h = (ch >> 5) & 15, c = ch & 31;
  int tid = threadIdx.x;
  int t = tid >> 2, seg = tid & 3;   // t = output row (d for P, j for Zt)
  const float* krow = kn + ((size_t)(b * T_ + c * 64 + t)) * D_ + h * 64;
  #pragma unroll
  for (int g = 0; g < 4; g++) {
    int o = t * 64 + seg * 16 + 4 * g;
    *(float4*)&Ksh[t][seg * 16 + 4 * g]  = *(const float4*)&krow[seg * 16 + 4 * g];
    *(float4*)&Wksh[t][seg * 16 + 4 * g] = *(const float4*)&Wkbuf[(size_t)ch * 4096 + o];
    *(float4*)&U0sh[t][seg * 16 + 4 * g] = *(const float4*)&U0buf[(size_t)ch * 4096 + o];
  }
  __syncthreads();
  int d0 = seg * 16;
  float accP[16], accZ[16];
  #pragma unroll
  for (int r = 0; r < 16; r++) { accP[r] = 0.f; accZ[r] = 0.f; }
  for (int s = 0; s < 64; s++) {
    float kt = Ksh[s][t];    // scalar for P row d=t
    float u  = U0sh[s][t];   // scalar for Z row j=t
    #pragma unroll
    for (int g = 0; g < 4; g++) {
      float4 w4 = *(float4*)&Wksh[s][d0 + 4 * g];
      float4 k4 = *(float4*)&Ksh[s][d0 + 4 * g];
      accP[4*g+0] += kt * w4.x; accP[4*g+1] += kt * w4.y; accP[4*g+2] += kt * w4.z; accP[4*g+3] += kt * w4.w;
      accZ[4*g+0] += u * k4.x;  accZ[4*g+1] += u * k4.y;  accZ[4*g+2] += u * k4.z;  accZ[4*g+3] += u * k4.w;
    }
  }
  float* zrow = kn + ((size_t)(b * T_ + c * 64 + t)) * D_ + h * 64;
  #pragma unroll
  for (int g = 0; g < 4; g++) {
    float4 pv;
    pv.x = ((d0 + 4*g + 0) == t ? 1.f : 0.f) - accP[4*g+0];
    pv.y = ((d0 + 4*g + 1) == t ? 1.f : 0.f) - accP[4*g+1];
    pv.z = ((d0 + 4*g + 2) == t ? 1.f : 0.f) - accP[4*g+2];
    pv.w = ((d0 + 4*g + 3) == t ? 1.f : 0.f) - accP[4*g+3];
    // slot-major: slot f = seg*4+g, row d = t
    *(float4*)&Pbuf[(size_t)ch * 4096 + (size_t)(seg * 4 + g) * 256 + (size_t)t * 4] = pv;
    float4 zv = {accZ[4*g+0], accZ[4*g+1], accZ[4*g+2], accZ[4*g+3]};
    *(float4*)&zrow[d0 + 4 * g] = zv;
  }
}

// ---------- state scan: S_{c+1} = P_c S_c + Z_c; Sbuf transposed [ch][j][d] ----------
__global__ __launch_bounds__(256) void state_kernel(
    const float* __restrict__ kn /*Zt*/, const float* __restrict__ Pbuf /*slot-major*/,
    float* __restrict__ Sbuf) {
  __shared__ __align__(16) float Pl[2][4096];
  int bid = blockIdx.x;
  int bh = bid & 31, js = bid >> 5;
  int h = bh & 15, b = bh >> 4;
  int tid = threadIdx.x;
  int wv = tid >> 6, lane = tid & 63;   // lane = d
  int j0 = js * 4 + wv;                 // this wave's column
  float s0 = 0.f;
  const size_t bhNC = (size_t)bh * NC_;
  const float* Pg0 = Pbuf + bhNC * 4096;
  #pragma unroll
  for (int g = 0; g < 4; g++)
    __builtin_amdgcn_global_load_lds(
        (const __attribute__((address_space(1))) void*)(Pg0 + (g * 256 + tid) * 4),
        (__attribute__((address_space(3))) void*)&Pl[0][(g * 256 + tid) * 4], 16, 0, 0);
  float zn = kn[((size_t)(b * T_ + j0)) * D_ + h * 64 + lane];
  int cur = 0;
  #pragma unroll 1
  for (int c = 0; c < NC_; c++) {
    __syncthreads();            // implies vmcnt(0) drain: buf[cur] ready for all waves
    float z = zn;
    size_t ch = bhNC + c;
    if (c + 1 < NC_) {
      const float* Pg = Pbuf + (ch + 1) * 4096;
      #pragma unroll
      for (int g = 0; g < 4; g++)
        __builtin_amdgcn_global_load_lds(
            (const __attribute__((address_space(1))) void*)(Pg + (g * 256 + tid) * 4),
            (__attribute__((address_space(3))) void*)&Pl[cur ^ 1][(g * 256 + tid) * 4], 16, 0, 0);
      zn = kn[((size_t)(b * T_ + (c + 1) * 64 + j0)) * D_ + h * 64 + lane];
    }
    Sbuf[ch * 4096 + (size_t)j0 * 64 + lane] = s0;
    float acc = z;
    #pragma unroll
    for (int f = 0; f < 16; f++) {
      floatx4 pv = *(floatx4*)&Pl[cur][f * 256 + lane * 4];
      acc += pv.x * rdlane(s0, f * 4 + 0);
      acc += pv.y * rdlane(s0, f * 4 + 1);
      acc += pv.z * rdlane(s0, f * 4 + 2);
      acc += pv.w * rdlane(s0, f * 4 + 3);
    }
    s0 = acc;
    cur ^= 1;
  }
}

// ---------- O = O0 + Qeff*S_c (S transposed layout), fused RMSNorm + bf16 cast ----------
__global__ __launch_bounds__(256) void ophase_kernel(
    const float* __restrict__ qn /*Qeff*/, const float* __restrict__ Sbuf,
    const float* __restrict__ O0buf, const float* __restrict__ rms_g,
    ushort* __restrict__ ob) {
  __shared__ float Ssht[64][68];
  __shared__ float QshT[64][65];
  __shared__ float part[64][4];
  int ch = blockIdx.x;
  int b = ch >> 9, h = (ch >> 5) & 15, c = ch & 31;
  int tid = threadIdx.x;
  int t = tid & 63, jg = tid >> 6;
  #pragma unroll
  for (int g = 0; g < 4; g++) {
    int idx = tid + g * 256;
    *(float4*)&Ssht[idx >> 4][(idx & 15) * 4] =
        *(const float4*)&Sbuf[(size_t)ch * 4096 + (size_t)idx * 4];
  }
  #pragma unroll
  for (int g = 0; g < 4; g++) {
    int idx = tid + g * 256;
    int row = idx >> 4, c4 = idx & 15;
    float4 qv = *(const float4*)&qn[((size_t)(b * T_ + c * 64 + row)) * D_ + h * 64 + c4 * 4];
    QshT[c4 * 4 + 0][row] = qv.x;
    QshT[c4 * 4 + 1][row] = qv.y;
    QshT[c4 * 4 + 2][row] = qv.z;
    QshT[c4 * 4 + 3][row] = qv.w;
  }
  float o[16];
  #pragma unroll
  for (int g = 0; g < 4; g++) {
    float4 o4 = *(const float4*)&O0buf[(size_t)ch * 4096 + t * 64 + jg * 16 + g * 4];
    o[4*g+0] = o4.x; o[4*g+1] = o4.y; o[4*g+2] = o4.z; o[4*g+3] = o4.w;
  }
  __syncthreads();
  for (int d4 = 0; d4 < 16; d4++) {
    float q0 = QshT[d4 * 4 + 0][t];
    float q1 = QshT[d4 * 4 + 1][t];
    float q2 = QshT[d4 * 4 + 2][t];
    float q3 = QshT[d4 * 4 + 3][t];
    #pragma unroll
    for (int r = 0; r < 16; r++) {
      float4 s4 = *(float4*)&Ssht[jg * 16 + r][d4 * 4];
      o[r] += q0 * s4.x + q1 * s4.y + q2 * s4.z + q3 * s4.w;
    }
  }
  float ss = 0.f;
  #pragma unroll
  for (int r = 0; r < 16; r++) ss += o[r] * o[r];
  part[t][jg] = ss;
  __syncthreads();
  float tot = part[t][0] + part[t][1] + part[t][2] + part[t][3];
  float sc = rsqrtf(tot * (1.f / 64.f) + 1e-6f);
  ushort* orow = &ob[((size_t)(b * T_ + c * 64 + t)) * D_ + h * 64];
  #pragma unroll
  for (int g = 0; g < 4; g++) {
    float4 g4 = *(const float4*)&rms_g[jg * 16 + g * 4];
    ushort4 r4;
    r4.x = f2bf(o[4*g+0] * sc * g4.x); r4.y = f2bf(o[4*g+1] * sc * g4.y);
    r4.z = f2bf(o[4*g+2] * sc * g4.z); r4.w = f2bf(o[4*g+3] * sc * g4.w);
    *(ushort4*)&orow[jg * 16 + g * 4] = r4;
  }
}

extern "C" void kernel_launch(void* const* d_in, const int* in_sizes, int n_in,
                              void* d_out, int out_size, void* d_ws, size_t ws_size,
                              hipStream_t stream) {
  const float* x  = (const float*)d_in[0];
  const float* Wq = (const float*)d_in[1];
  const float* Wk = (const float*)d_in[2];
  const float* Wv = (const float*)d_in[3];
  const float* Wb = (const float*)d_in[4];
  const float* cq = (const float*)d_in[5];
  const float* ck = (const float*)d_in[6];
  const float* cv = (const float*)d_in[7];
  const float* rg = (const float*)d_in[8];
  const float* Wo = (const float*)d_in[9];
  float* out = (float*)d_out;
  char* ws = (char*)d_ws;
  const size_t MiB = 1ull << 20;
  ushort* xb   = (ushort*)(ws + 0);         // dead after QKV gemm
  ushort* Wqt  = (ushort*)(ws + 8 * MiB);   // Wqt/Wkt/Wvt contiguous = [3072][1024] bf16
  ushort* Wkt  = (ushort*)(ws + 10 * MiB);
  ushort* Wvt  = (ushort*)(ws + 12 * MiB);
  ushort* Wot  = (ushort*)(ws + 14 * MiB);  // live to end
  float* qkv   = (float*)(ws + 16 * MiB);   // [4096][3072] fp32, dead after conv
  float* qn    = (float*)(ws + 64 * MiB);   // then Qeff in-place
  float* kn    = (float*)(ws + 80 * MiB);   // then Zt in-place
  float* vn    = (float*)(ws + 96 * MiB);   // dead after prep1
  float* beta  = (float*)(ws + 112 * MiB);  // 256 KiB
  float* WbT   = (float*)(ws + 112 * MiB + 256 * 1024);  // 64 KiB
  float* Wkbuf = (float*)(ws + 16 * MiB);   // over qkv (dead after conv)
  float* U0buf = (float*)(ws + 32 * MiB);
  float* Pbuf  = (float*)(ws + 48 * MiB);   // P (prep2c out, state in)
  float* O0buf = (float*)(ws + 96 * MiB);   // over vn (after prep1)
  float* Sbuf  = (float*)(ws + 16 * MiB);   // over Wkbuf (dead after prep2c)
  ushort* ob   = (ushort*)(ws + 0);         // over xb (after QKV gemm)

  hipLaunchKernelGGL(cast_kernel, dim3(M_ * D_ / 4 / 256), dim3(256), 0, stream,
                     x, xb, M_ * D_ / 4);
  dim3 tb(32, 8);
  hipLaunchKernelGGL(transpose_cast_kernel, dim3(32, 32), tb, 0, stream, Wq, Wqt, D_, D_);
  hipLaunchKernelGGL(transpose_cast_kernel, dim3(32, 32), tb, 0, stream, Wk, Wkt, D_, D_);
  hipLaunchKernelGGL(transpose_cast_kernel, dim3(32, 32), tb, 0, stream, Wv, Wvt, D_, D_);
  hipLaunchKernelGGL(transpose_cast_kernel, dim3(32, 32), tb, 0, stream, Wo, Wot, D_, D_);
  hipLaunchKernelGGL(transpose_wb_kernel, dim3(64), dim3(256), 0, stream, Wb, WbT);

  hipLaunchKernelGGL(gemm128_kernel, dim3(M_ / 128, QKVN_ / 128), dim3(256), 0, stream,
                     xb, Wqt, qkv, M_, QKVN_, D_);

  hipLaunchKernelGGL(beta_kernel, dim3(M_), dim3(256), 0, stream, x, WbT, beta);
  hipLaunchKernelGGL(conv_kernel, dim3(M_), dim3(256), 0, stream,
                     qkv, cq, ck, cv, qn, kn, vn);

  hipLaunchKernelGGL(prep1_kernel, dim3(NCH_), dim3(256), 0, stream,
                     kn, vn, beta, Wkbuf, U0buf);
  hipLaunchKernelGGL(prep2ab_kernel, dim3(NCH_), dim3(256), 0, stream,
                     qn, kn, Wkbuf, U0buf, O0buf);
  hipLaunchKernelGGL(prep2c_kernel, dim3(NCH_), dim3(256), 0, stream,
                     kn, Wkbuf, U0buf, Pbuf);
  hipLaunchKernelGGL(state_kernel, dim3(512), dim3(256), 0, stream,
                     kn, Pbuf, Sbuf);
  hipLaunchKernelGGL(ophase_kernel, dim3(NCH_), dim3(256), 0, stream,
                     qn, Sbuf, O0buf, rg, ob);
  hipLaunchKernelGGL(gemm128_kernel, dim3(M_ / 128, D_ / 128), dim3(256), 0, stream,
                     ob, Wot, out, M_, D_, D_);
}

// Round 11
// 357.837 us; speedup vs baseline: 1.0605x; 1.0605x over previous
//
#include <hip/hip_runtime.h>
#include <hip/hip_bf16.h>
#include <math.h>

#define B_ 2
#define T_ 2048
#define D_ 1024
#define H_ 16
#define DH_ 64
#define M_ (B_*T_)   // 4096 rows
#define NC_ 32       // chunks per sequence (T/64)
#define CS_ 64       // chunk size
#define NCH_ (B_*H_*NC_)  // 1024 chunk-heads
#define QKVN_ 3072   // fused QKV gemm N

typedef __attribute__((ext_vector_type(4))) float floatx4;
typedef __attribute__((ext_vector_type(8))) short short8;

__device__ __forceinline__ ushort f2bf(float f) {
  union { float f; unsigned u; } c; c.f = f;
  unsigned r = (c.u + 0x7FFFu + ((c.u >> 16) & 1u)) >> 16;  // RNE
  return (ushort)r;
}
__device__ __forceinline__ float siluf(float u) {
  return u / (1.f + __expf(-u));
}
__device__ __forceinline__ float f4get(const float4& v, int j) {
  return j == 0 ? v.x : j == 1 ? v.y : j == 2 ? v.z : v.w;
}
__device__ __forceinline__ float rdlane(float v, int l) {
  return __int_as_float(__builtin_amdgcn_readlane(__float_as_int(v), l));
}
// swizzled chunk index for K tiles: chunk c (0..15) of row r stored at c ^ (r>>4)
__device__ __forceinline__ int ksw(int r, int c) { return ((c ^ (r >> 4)) << 2); }

// ---------- cast f32 -> bf16, n4 = n/4 ----------
__global__ void cast_kernel(const float* __restrict__ in, ushort* __restrict__ out, int n4) {
  int i = blockIdx.x * blockDim.x + threadIdx.x;
  if (i >= n4) return;
  float4 v = ((const float4*)in)[i];
  ushort4 o;
  o.x = f2bf(v.x); o.y = f2bf(v.y); o.z = f2bf(v.z); o.w = f2bf(v.w);
  ((ushort4*)out)[i] = o;
}

// ---------- transpose + cast: W[K][N] f32 -> Wt[N][K] bf16 ----------
__global__ void transpose_cast_kernel(const float* __restrict__ W, ushort* __restrict__ Wt,
                                      int K, int N) {
  __shared__ float tile[32][33];
  int tx = threadIdx.x, ty = threadIdx.y;
  int n0 = blockIdx.x * 32, k0 = blockIdx.y * 32;
  #pragma unroll
  for (int i = 0; i < 32; i += 8)
    tile[ty + i][tx] = W[(size_t)(k0 + ty + i) * N + n0 + tx];
  __syncthreads();
  #pragma unroll
  for (int i = 0; i < 32; i += 8)
    Wt[(size_t)(n0 + ty + i) * K + k0 + tx] = f2bf(tile[tx][ty + i]);
}

// ---------- transpose Wb[1024][16] -> WbT[16][1024] (fp32) ----------
__global__ void transpose_wb_kernel(const float* __restrict__ Wb, float* __restrict__ WbT) {
  int bk = blockIdx.x;
  int tid = threadIdx.x;
  int kl = tid >> 4, h = tid & 15;
  int k = bk * 16 + kl;
  WbT[(size_t)h * D_ + k] = Wb[(size_t)k * H_ + h];
}

// ---------- bf16 MFMA GEMM, 2-phase counted-vmcnt pipeline + XCD supertile swizzle ----------
__global__ __launch_bounds__(256) void gemm128_kernel(
    const ushort* __restrict__ A, const ushort* __restrict__ Bt,
    float* __restrict__ C, int M, int N, int K) {
  __shared__ ushort lA[2][128 * 32];
  __shared__ ushort lB[2][128 * 32];
  int tid = threadIdx.x;
  int wave = tid >> 6, lane = tid & 63;
  int wm = wave >> 1, wn = wave & 1;
  int m16 = lane & 15, q4 = lane >> 4;
  // XCD-aware bijective swizzle with 8x8 supertiles
  int nbm = gridDim.x, nbn = gridDim.y;
  int lin = blockIdx.y * nbm + blockIdx.x;
  int cpx = (nbm * nbn) >> 3;
  int swz = (lin & 7) * cpx + (lin >> 3);
  int stn = nbn >> 3;
  int st = swz >> 6, in_ = swz & 63;
  int stm = st / stn, soff = st - stm * stn;
  int bm = stm * 8 + (in_ & 7);
  int bn = soff * 8 + (in_ >> 3);
  floatx4 acc[4][4] = {};
  int srow = tid >> 2;
  int sk8 = tid & 3;
  const ushort* Ag = A + (size_t)(bm * 128 + srow) * K + sk8 * 8;
  const ushort* Bg = Bt + (size_t)(bn * 128 + srow) * K + sk8 * 8;
  int nks = K >> 5;

#define GSTAGE(bufi, kk0)                                                       \
  {                                                                             \
    __builtin_amdgcn_global_load_lds(                                           \
        (const __attribute__((address_space(1))) void*)(Ag + (kk0)),            \
        (__attribute__((address_space(3))) void*)&lA[bufi][tid * 8], 16, 0, 0); \
    __builtin_amdgcn_global_load_lds(                                           \
        (const __attribute__((address_space(1))) void*)(Ag + (size_t)64 * K + (kk0)), \
        (__attribute__((address_space(3))) void*)&lA[bufi][tid * 8 + 2048], 16, 0, 0); \
    __builtin_amdgcn_global_load_lds(                                           \
        (const __attribute__((address_space(1))) void*)(Bg + (kk0)),            \
        (__attribute__((address_space(3))) void*)&lB[bufi][tid * 8], 16, 0, 0); \
    __builtin_amdgcn_global_load_lds(                                           \
        (const __attribute__((address_space(1))) void*)(Bg + (size_t)64 * K + (kk0)), \
        (__attribute__((address_space(3))) void*)&lB[bufi][tid * 8 + 2048], 16, 0, 0); \
  }

  GSTAGE(0, 0);
  int cur = 0;
  #pragma unroll 1
  for (int ks = 0; ks < nks; ++ks) {
    if (ks + 1 < nks) {
      GSTAGE(cur ^ 1, (ks + 1) * 32);
      asm volatile("s_waitcnt vmcnt(4)" ::: "memory");
    } else {
      asm volatile("s_waitcnt vmcnt(0)" ::: "memory");
    }
    __builtin_amdgcn_s_barrier();       // buf[cur] staged & visible
    __builtin_amdgcn_sched_barrier(0);
    short8 af[4], bf[4];
    #pragma unroll
    for (int i = 0; i < 4; i++) {
      af[i] = *(short8*)&lA[cur][(wm * 64 + i * 16 + m16) * 32 + q4 * 8];
      bf[i] = *(short8*)&lB[cur][(wn * 64 + i * 16 + m16) * 32 + q4 * 8];
    }
    #pragma unroll
    for (int mi = 0; mi < 4; mi++)
      #pragma unroll
      for (int nj = 0; nj < 4; nj++)
        acc[mi][nj] = __builtin_amdgcn_mfma_f32_16x16x32_bf16(af[mi], bf[nj], acc[mi][nj], 0, 0, 0);
    __builtin_amdgcn_s_barrier();       // all waves done reading buf[cur]
    cur ^= 1;
  }
#undef GSTAGE
  float* Cb = C + (size_t)(bm * 128) * N + bn * 128;
  #pragma unroll
  for (int mi = 0; mi < 4; mi++) {
    #pragma unroll
    for (int nj = 0; nj < 4; nj++) {
      #pragma unroll
      for (int i = 0; i < 4; i++) {
        int row = wm * 64 + mi * 16 + q4 * 4 + i;
        int col = wn * 64 + nj * 16 + m16;
        Cb[(size_t)row * N + col] = acc[mi][nj][i];
      }
    }
  }
}

// ---------- beta = sigmoid(x @ Wb): blocked GEMV, 16 rows/block ----------
// WbT staged ONCE per block into 64KB LDS with XOR-(h&7) float4-index swizzle
// (same involution on write and read; h and h+8 share banks -> 2-way = free).
// Thread (r,h) computes one full K=1024 dot; x rows L1-broadcast across the 16
// h-threads; 4-accumulator rotation (static indices). WbT traffic 256MB -> 16MB.
__global__ __launch_bounds__(256) void beta_kernel(const float* __restrict__ x,
                                                   const float* __restrict__ WbT,
                                                   float* __restrict__ beta) {
  __shared__ __align__(16) float4 wsh[16][256];   // 64 KB
  int tid = threadIdx.x;
  const float4* Wb4 = (const float4*)WbT;
  #pragma unroll
  for (int i = 0; i < 16; i++) {
    int idx = i * 256 + tid;
    int h = idx >> 8, c = idx & 255;
    wsh[h][c ^ (h & 7)] = Wb4[h * 256 + c];
  }
  __syncthreads();
  int r = tid >> 4, h = tid & 15;
  int hs = h & 7;
  int row = blockIdx.x * 16 + r;
  const float4* xr = (const float4*)(x + (size_t)row * D_);
  float acc0 = 0.f, acc1 = 0.f, acc2 = 0.f, acc3 = 0.f;
  #pragma unroll 8
  for (int c = 0; c < 256; c += 4) {
    float4 x0 = xr[c + 0], x1 = xr[c + 1], x2 = xr[c + 2], x3 = xr[c + 3];
    float4 w0 = wsh[h][(c + 0) ^ hs];
    float4 w1 = wsh[h][(c + 1) ^ hs];
    float4 w2 = wsh[h][(c + 2) ^ hs];
    float4 w3 = wsh[h][(c + 3) ^ hs];
    acc0 += x0.x * w0.x + x0.y * w0.y + x0.z * w0.z + x0.w * w0.w;
    acc1 += x1.x * w1.x + x1.y * w1.y + x1.z * w1.z + x1.w * w1.w;
    acc2 += x2.x * w2.x + x2.y * w2.y + x2.z * w2.z + x2.w * w2.w;
    acc3 += x3.x * w3.x + x3.y * w3.y + x3.z * w3.z + x3.w * w3.w;
  }
  float s = (acc0 + acc1) + (acc2 + acc3);
  beta[(size_t)row * H_ + h] = 1.f / (1.f + __expf(-s));
}

// ---------- causal depthwise conv(K=4) + silu, l2norm for q,k ----------
__global__ __launch_bounds__(256) void conv_kernel(
    const float* __restrict__ qkv,
    const float* __restrict__ cq, const float* __restrict__ ck, const float* __restrict__ cv,
    float* __restrict__ qo, float* __restrict__ ko, float* __restrict__ vo) {
  int row = blockIdx.x;
  int t = row & (T_ - 1);
  int tid = threadIdx.x;
  int c0 = tid * 4;
  float4 zf = {0.f, 0.f, 0.f, 0.f};
  float4 xq[4], xk[4], xv[4];
  #pragma unroll
  for (int i = 0; i < 4; i++) {
    int tt = t - 3 + i;
    if (tt >= 0) {
      const float* rp = qkv + (size_t)(row - 3 + i) * QKVN_;
      xq[i] = *(const float4*)(rp + c0);
      xk[i] = *(const float4*)(rp + 1024 + c0);
      xv[i] = *(const float4*)(rp + 2048 + c0);
    } else { xq[i] = zf; xk[i] = zf; xv[i] = zf; }
  }
  float yq[4], yk[4], yv[4];
  float pq = 0.f, pk = 0.f;
  #pragma unroll
  for (int j = 0; j < 4; j++) {
    float4 wq = ((const float4*)cq)[c0 + j];
    float4 wk = ((const float4*)ck)[c0 + j];
    float4 wv = ((const float4*)cv)[c0 + j];
    float sq = 0.f, sk = 0.f, sv = 0.f;
    #pragma unroll
    for (int i = 0; i < 4; i++) {
      sq += f4get(wq, i) * f4get(xq[i], j);
      sk += f4get(wk, i) * f4get(xk[i], j);
      sv += f4get(wv, i) * f4get(xv[i], j);
    }
    yq[j] = siluf(sq); yk[j] = siluf(sk); yv[j] = siluf(sv);
    pq += yq[j] * yq[j]; pk += yk[j] * yk[j];
  }
  #pragma unroll
  for (int off = 1; off < 16; off <<= 1) {
    pq += __shfl_xor(pq, off, 16);
    pk += __shfl_xor(pk, off, 16);
  }
  float rq = rsqrtf(pq + 1e-6f), rk = rsqrtf(pk + 1e-6f);
  float4 oq = {yq[0]*rq, yq[1]*rq, yq[2]*rq, yq[3]*rq};
  float4 okk = {yk[0]*rk, yk[1]*rk, yk[2]*rk, yk[3]*rk};
  float4 ov = {yv[0], yv[1], yv[2], yv[3]};
  *(float4*)(qo + (size_t)row * D_ + c0) = oq;
  *(float4*)(ko + (size_t)row * D_ + c0) = okk;
  *(float4*)(vo + (size_t)row * D_ + c0) = ov;
}

// ================= chunked delta rule =================
// prep1: A = strict_tril(diag(b)KK^T); solve (I+A)Wk = diag(b)K and (I+A)U0 = diag(b)V
// A-phase via split-bf16 MFMA. hi/lo split happens IN the staging loop (load kn
// fp32 -> split 8 values in registers -> ds_write to bank-staggered KH/KL).
// LDS layout: row stride 160B, XOR-16 swizzle applied identically on write-col
// and read-col (involution). A = hh + hl + lh MFMAs (error ~2^-23 rel).
// Solve phases unchanged (R3-verified).
__global__ __launch_bounds__(256) void prep1_kernel(
    const float* __restrict__ kn, const float* __restrict__ vn,
    const float* __restrict__ beta,
    float* __restrict__ Wkbuf, float* __restrict__ U0buf) {
  __shared__ __align__(16) float Ash[64 * 68];   // A[t][s] row-major, stride 68
  __shared__ float bsh[64];
  // union region: KH/KL (during A compute) aliased with Tsh/Msh/Xsh (after)
  __shared__ __align__(16) float uni[5312];
  ushort* KH = (ushort*)uni;                                // 64 rows x 160B = 10240B
  ushort* KL = (ushort*)uni + 5120;                         // next 10240B
  float (*Tsh)[16][20] = (float (*)[16][20])uni;            // [4][16][20] = 1280
  float (*Msh)[16][20] = (float (*)[16][20])(uni + 1280);   // [6][16][20] = 1920
  float (*Xsh)[132] = (float (*)[132])(uni + 3200);         // [16][132]  = 2112

  int ch = blockIdx.x;
  int b = ch >> 9, h = (ch >> 5) & 15, c = ch & 31;
  int tid = threadIdx.x;
  int t = tid >> 2, seg = tid & 3;
  int wave = tid >> 6, lane = tid & 63;
  int r = lane >> 2, q = lane & 3;   // r == t&15, q == seg
  int m16 = lane & 15, oct = lane >> 4;
  const float* kg = kn + ((size_t)(b * T_ + c * 64)) * D_ + h * 64;
  // stage KH/KL: 2 passes x 256 threads x (8 bf16 = 16B dest); load fp32 from kn,
  // split hi/lo in registers, write to swizzled column (involution with read).
  {
    #pragma unroll
    for (int p = 0; p < 2; p++) {
      int idx = p * 256 + tid;          // 16B dest unit
      int row = idx >> 3, cb = (idx & 7) * 16;
      int scb = cb ^ ((row & 7) << 4);  // source byte col (bf16 units)
      const float* src = kg + (size_t)row * D_ + (scb >> 1);
      float4 va = *(const float4*)src;
      float4 vb = *(const float4*)(src + 4);
      float v[8] = {va.x, va.y, va.z, va.w, vb.x, vb.y, vb.z, vb.w};
      short8 hi8, lo8;
      #pragma unroll
      for (int j = 0; j < 8; j++) {
        unsigned u = __float_as_uint(v[j]);
        hi8[j] = (short)(u >> 16);                      // truncated bf16 hi
        lo8[j] = (short)f2bf(v[j] - __uint_as_float(u & 0xFFFF0000u));
      }
      *(short8*)((char*)KH + row * 160 + cb) = hi8;
      *(short8*)((char*)KL + row * 160 + cb) = lo8;
    }
  }
  if (tid < 64) bsh[tid] = beta[((size_t)(b * T_ + c * 64 + tid)) * H_ + h];
  __syncthreads();
  // A[t][s] = (t>s) ? b_t * (k_t . k_s) : 0 — split-bf16 MFMA; wave w owns row-tile w
  {
    floatx4 acc[4] = {};
    #pragma unroll
    for (int ks = 0; ks < 2; ks++) {
      int ob = (ks * 64 + oct * 16) ^ ((m16 & 7) << 4);
      short8 fah = *(short8*)((char*)KH + (wave * 16 + m16) * 160 + ob);
      short8 fal = *(short8*)((char*)KL + (wave * 16 + m16) * 160 + ob);
      #pragma unroll
      for (int si = 0; si < 4; si++) {
        short8 fbh = *(short8*)((char*)KH + (si * 16 + m16) * 160 + ob);
        short8 fbl = *(short8*)((char*)KL + (si * 16 + m16) * 160 + ob);
        acc[si] = __builtin_amdgcn_mfma_f32_16x16x32_bf16(fah, fbh, acc[si], 0, 0, 0);
        acc[si] = __builtin_amdgcn_mfma_f32_16x16x32_bf16(fah, fbl, acc[si], 0, 0, 0);
        acc[si] = __builtin_amdgcn_mfma_f32_16x16x32_bf16(fal, fbh, acc[si], 0, 0, 0);
      }
    }
    // D layout: row-in-tile = oct*4+rr, col = m16 (verified C/D mapping)
    #pragma unroll
    for (int si = 0; si < 4; si++) {
      #pragma unroll
      for (int rr = 0; rr < 4; rr++) {
        int row = wave * 16 + oct * 4 + rr;
        int col = si * 16 + m16;
        float bt = bsh[row];
        Ash[row * 68 + col] = (row > col) ? bt * acc[si][rr] : 0.f;
      }
    }
  }
  // RHS (residual Y) in registers: row t, 16 K-cols + 16 V-cols (fp32 from global)
  float xk[16], xv[16];
  {
    float bt = bsh[t];
    const float* krow = kn + ((size_t)(b * T_ + c * 64 + t)) * D_ + h * 64;
    const float* vrow = vn + ((size_t)(b * T_ + c * 64 + t)) * D_ + h * 64;
    #pragma unroll
    for (int g = 0; g < 4; g++) {
      float4 kv = *(const float4*)&krow[seg * 16 + 4 * g];
      float4 vv = *(const float4*)&vrow[seg * 16 + 4 * g];
      xk[4*g+0] = bt * kv.x; xk[4*g+1] = bt * kv.y; xk[4*g+2] = bt * kv.z; xk[4*g+3] = bt * kv.w;
      xv[4*g+0] = bt * vv.x; xv[4*g+1] = bt * vv.y; xv[4*g+2] = bt * vv.z; xv[4*g+3] = bt * vv.w;
    }
  }
  __syncthreads();   // Ash ready; KH/KL dead -> Tsh/Msh/Xsh region live
  // Phase A: wave-parallel 16x16 diagonal-block inverse via fwd substitution on I
  {
    float a[16];
    #pragma unroll
    for (int i = 0; i < 16; i++) a[i] = Ash[(wave * 16 + r) * 68 + wave * 16 + i];
    float4 w4 = {0.f, 0.f, 0.f, 0.f};
    if ((r >> 2) == q) ((float*)&w4)[r & 3] = 1.f;
    #pragma unroll
    for (int i = 0; i < 15; i++) {
      int src = i * 4 + q;
      float4 wi;
      wi.x = __shfl(w4.x, src, 64);
      wi.y = __shfl(w4.y, src, 64);
      wi.z = __shfl(w4.z, src, 64);
      wi.w = __shfl(w4.w, src, 64);
      if (r > i) {
        w4.x -= a[i] * wi.x; w4.y -= a[i] * wi.y;
        w4.z -= a[i] * wi.z; w4.w -= a[i] * wi.w;
      }
    }
    *(float4*)&Tsh[wave][r][q * 4] = w4;
  }
  __syncthreads();   // Tsh visible to all waves
  // Phase B: M_wk = A_wk * T_kk (wave-local write, wave-local read)
  for (int k = 0; k < wave; k++) {
    float4 m4 = {0.f, 0.f, 0.f, 0.f};
    #pragma unroll
    for (int i = 0; i < 16; i++) {
      float aik = Ash[(wave * 16 + r) * 68 + k * 16 + i];
      float4 tk = *(float4*)&Tsh[k][i][q * 4];
      m4.x += aik * tk.x; m4.y += aik * tk.y;
      m4.z += aik * tk.z; m4.w += aik * tk.w;
    }
    int mi = wave * (wave - 1) / 2 + k;
    *(float4*)&Msh[mi][r][q * 4] = m4;
  }
  // Block substitution k-loop
  float* wkout = &Wkbuf[(size_t)ch * 4096 + t * 64];
  float* u0out = &U0buf[(size_t)ch * 4096 + t * 64];
  for (int k = 0; k < 4; k++) {
    if (wave == k) {   // publish residual Y_k
      #pragma unroll
      for (int g = 0; g < 4; g++) {
        float4 k4 = {xk[4*g+0], xk[4*g+1], xk[4*g+2], xk[4*g+3]};
        float4 v4 = {xv[4*g+0], xv[4*g+1], xv[4*g+2], xv[4*g+3]};
        *(float4*)&Xsh[r][seg * 16 + 4 * g] = k4;
        *(float4*)&Xsh[r][64 + seg * 16 + 4 * g] = v4;
      }
    }
    __syncthreads();
    if (wave == k) {
      // X_k = T_kk * Y_k -> final output, straight to global
      float nk[16], nv[16];
      #pragma unroll
      for (int i2 = 0; i2 < 16; i2++) { nk[i2] = 0.f; nv[i2] = 0.f; }
      #pragma unroll
      for (int i = 0; i < 16; i++) {
        float tc = Tsh[k][r][i];
        #pragma unroll
        for (int g = 0; g < 4; g++) {
          float4 yk = *(float4*)&Xsh[i][seg * 16 + 4 * g];
          float4 yv = *(float4*)&Xsh[i][64 + seg * 16 + 4 * g];
          nk[4*g+0] += tc * yk.x; nk[4*g+1] += tc * yk.y;
          nk[4*g+2] += tc * yk.z; nk[4*g+3] += tc * yk.w;
          nv[4*g+0] += tc * yv.x; nv[4*g+1] += tc * yv.y;
          nv[4*g+2] += tc * yv.z; nv[4*g+3] += tc * yv.w;
        }
      }
      #pragma unroll
      for (int g = 0; g < 4; g++) {
        float4 k4 = {nk[4*g+0], nk[4*g+1], nk[4*g+2], nk[4*g+3]};
        float4 v4 = {nv[4*g+0], nv[4*g+1], nv[4*g+2], nv[4*g+3]};
        *(float4*)&wkout[seg * 16 + 4 * g] = k4;
        *(float4*)&u0out[seg * 16 + 4 * g] = v4;
      }
    } else if (wave > k) {
      // Y_i -= M_ik * Y_k   (== A_ik * X_k)
      int mi = wave * (wave - 1) / 2 + k;
      #pragma unroll
      for (int i = 0; i < 16; i++) {
        float mc = Msh[mi][r][i];
        #pragma unroll
        for (int g = 0; g < 4; g++) {
          float4 yk = *(float4*)&Xsh[i][seg * 16 + 4 * g];
          float4 yv = *(float4*)&Xsh[i][64 + seg * 16 + 4 * g];
          xk[4*g+0] -= mc * yk.x; xk[4*g+1] -= mc * yk.y;
          xk[4*g+2] -= mc * yk.z; xk[4*g+3] -= mc * yk.w;
          xv[4*g+0] -= mc * yv.x; xv[4*g+1] -= mc * yv.y;
          xv[4*g+2] -= mc * yv.z; xv[4*g+3] -= mc * yv.w;
        }
      }
    }
    __syncthreads();
  }
}

// prep2ab: fused prep2a+prep2b. Phase 1: L = tril(Q K^T) -> Lsh (LDS, no HBM
// roundtrip), with 4x4 register output tiling (8 float4 reads / 64 FMAs per d4).
// Phase 2: reuse Qsh/Ksh LDS space for Wk/U0 staging, then
// O0 = L U0 ; Qeff = Q - L Wk (identical arithmetic order to the old kernels).
__global__ __launch_bounds__(256) void prep2ab_kernel(
    float* qn, const float* __restrict__ kn,
    const float* __restrict__ Wkbuf, const float* __restrict__ U0buf,
    float* __restrict__ O0buf) {
  __shared__ float Qsh[64][68];   // phase 2: Wksh
  __shared__ float Ksh[64][68];   // swizzled; phase 2: U0sh
  __shared__ float Lsh[64][68];
  float (*Wksh)[68] = Qsh;
  float (*U0sh)[68] = Ksh;
  int ch = blockIdx.x;
  int b = ch >> 9, h = (ch >> 5) & 15, c = ch & 31;
  int tid = threadIdx.x;
  int t = tid >> 2, seg = tid & 3;
  const float* qrow = qn + ((size_t)(b * T_ + c * 64 + t)) * D_ + h * 64;
  const float* krow = kn + ((size_t)(b * T_ + c * 64 + t)) * D_ + h * 64;
  #pragma unroll
  for (int g = 0; g < 4; g++) {
    *(float4*)&Qsh[t][seg * 16 + 4 * g] = *(const float4*)&qrow[seg * 16 + 4 * g];
    *(float4*)&Ksh[t][ksw(t, seg * 4 + g)] = *(const float4*)&krow[seg * 16 + 4 * g];
  }
  __syncthreads();
  // phase 1: L = tril(Q K^T) -> Lsh, 4x4 register tile per thread
  {
    int qt = tid >> 4, qs = tid & 15;
    int sws = qs >> 2;
    float acc[4][4];
    #pragma unroll
    for (int i = 0; i < 4; i++)
      #pragma unroll
      for (int j = 0; j < 4; j++) acc[i][j] = 0.f;
    for (int d4 = 0; d4 < 16; d4++) {
      float4 qv[4], ks[4];
      #pragma unroll
      for (int i = 0; i < 4; i++) qv[i] = *(float4*)&Qsh[qt * 4 + i][d4 * 4];
      #pragma unroll
      for (int j = 0; j < 4; j++) ks[j] = *(float4*)&Ksh[qs * 4 + j][((d4 ^ sws) << 2)];
      #pragma unroll
      for (int i = 0; i < 4; i++)
        #pragma unroll
        for (int j = 0; j < 4; j++)
          acc[i][j] += qv[i].x * ks[j].x + qv[i].y * ks[j].y
                     + qv[i].z * ks[j].z + qv[i].w * ks[j].w;
    }
    #pragma unroll
    for (int i = 0; i < 4; i++) {
      int row = qt * 4 + i;
      float4 ov;
      ov.x = (qs * 4 + 0 <= row) ? acc[i][0] : 0.f;
      ov.y = (qs * 4 + 1 <= row) ? acc[i][1] : 0.f;
      ov.z = (qs * 4 + 2 <= row) ? acc[i][2] : 0.f;
      ov.w = (qs * 4 + 3 <= row) ? acc[i][3] : 0.f;
      *(float4*)&Lsh[row][qs * 4] = ov;
    }
  }
  __syncthreads();   // L done; Qsh/Ksh dead -> stage Wk/U0 into their space
  #pragma unroll
  for (int g = 0; g < 4; g++) {
    int o = t * 64 + seg * 16 + 4 * g;
    *(float4*)&Wksh[t][seg * 16 + 4 * g] = *(const float4*)&Wkbuf[(size_t)ch * 4096 + o];
    *(float4*)&U0sh[t][seg * 16 + 4 * g] = *(const float4*)&U0buf[(size_t)ch * 4096 + o];
  }
  __syncthreads();
  // phase 2: O0 = L U0 ; Qeff = Q - L Wk (identical to old prep2b)
  int j0 = seg * 16;
  float o0[16], lw[16];
  #pragma unroll
  for (int r = 0; r < 16; r++) { o0[r] = 0.f; lw[r] = 0.f; }
  for (int s = 0; s <= t; s++) {
    float l = Lsh[t][s];
    #pragma unroll
    for (int g = 0; g < 4; g++) {
      float4 u = *(float4*)&U0sh[s][j0 + 4 * g];
      float4 w = *(float4*)&Wksh[s][j0 + 4 * g];
      o0[4*g+0] += l * u.x; o0[4*g+1] += l * u.y; o0[4*g+2] += l * u.z; o0[4*g+3] += l * u.w;
      lw[4*g+0] += l * w.x; lw[4*g+1] += l * w.y; lw[4*g+2] += l * w.z; lw[4*g+3] += l * w.w;
    }
  }
  float* qwrow = qn + ((size_t)(b * T_ + c * 64 + t)) * D_ + h * 64;
  #pragma unroll
  for (int g = 0; g < 4; g++) {
    float4 qv = *(const float4*)&qwrow[j0 + 4 * g];
    qv.x -= lw[4*g+0]; qv.y -= lw[4*g+1]; qv.z -= lw[4*g+2]; qv.w -= lw[4*g+3];
    *(float4*)&qwrow[j0 + 4 * g] = qv;
    float4 ov = {o0[4*g+0], o0[4*g+1], o0[4*g+2], o0[4*g+3]};
    *(float4*)&O0buf[(size_t)ch * 4096 + t * 64 + j0 + 4 * g] = ov;
  }
}

// prep2c: P[d][e] = I - (K^T Wk)[d][e], stored SLOT-MAJOR for state_kernel:
//         float4 #(f*64+d) of chunk = P[d][4f..4f+3]  (so a wave reading slot f,
//         all rows d, is one contiguous 1KB block).
//         Zt[j][d] = (U0^T K)[j][d] -> kn rows j (coalesced), unchanged.
__global__ __launch_bounds__(256) void prep2c_kernel(
    float* kn, const float* __restrict__ Wkbuf,
    const float* __restrict__ U0buf, float* __restrict__ Pbuf) {
  __shared__ float Ksh[64][68];
  __shared__ float Wksh[64][68];
  __shared__ float U0sh[64][68];
  int ch = blockIdx.x;
  int b = ch >> 9, h = (ch >> 5) & 15, c = ch & 31;
  int tid = threadIdx.x;
  int t = tid >> 2, seg = tid & 3;   // t = output row (d for P, j for Zt)
  const float* krow = kn + ((size_t)(b * T_ + c * 64 + t)) * D_ + h * 64;
  #pragma unroll
  for (int g = 0; g < 4; g++) {
    int o = t * 64 + seg * 16 + 4 * g;
    *(float4*)&Ksh[t][seg * 16 + 4 * g]  = *(const float4*)&krow[seg * 16 + 4 * g];
    *(float4*)&Wksh[t][seg * 16 + 4 * g] = *(const float4*)&Wkbuf[(size_t)ch * 4096 + o];
    *(float4*)&U0sh[t][seg * 16 + 4 * g] = *(const float4*)&U0buf[(size_t)ch * 4096 + o];
  }
  __syncthreads();
  int d0 = seg * 16;
  float accP[16], accZ[16];
  #pragma unroll
  for (int r = 0; r < 16; r++) { accP[r] = 0.f; accZ[r] = 0.f; }
  for (int s = 0; s < 64; s++) {
    float kt = Ksh[s][t];    // scalar for P row d=t
    float u  = U0sh[s][t];   // scalar for Z row j=t
    #pragma unroll
    for (int g = 0; g < 4; g++) {
      float4 w4 = *(float4*)&Wksh[s][d0 + 4 * g];
      float4 k4 = *(float4*)&Ksh[s][d0 + 4 * g];
      accP[4*g+0] += kt * w4.x; accP[4*g+1] += kt * w4.y; accP[4*g+2] += kt * w4.z; accP[4*g+3] += kt * w4.w;
      accZ[4*g+0] += u * k4.x;  accZ[4*g+1] += u * k4.y;  accZ[4*g+2] += u * k4.z;  accZ[4*g+3] += u * k4.w;
    }
  }
  float* zrow = kn + ((size_t)(b * T_ + c * 64 + t)) * D_ + h * 64;
  #pragma unroll
  for (int g = 0; g < 4; g++) {
    float4 pv;
    pv.x = ((d0 + 4*g + 0) == t ? 1.f : 0.f) - accP[4*g+0];
    pv.y = ((d0 + 4*g + 1) == t ? 1.f : 0.f) - accP[4*g+1];
    pv.z = ((d0 + 4*g + 2) == t ? 1.f : 0.f) - accP[4*g+2];
    pv.w = ((d0 + 4*g + 3) == t ? 1.f : 0.f) - accP[4*g+3];
    // slot-major: slot f = seg*4+g, row d = t
    *(float4*)&Pbuf[(size_t)ch * 4096 + (size_t)(seg * 4 + g) * 256 + (size_t)t * 4] = pv;
    float4 zv = {accZ[4*g+0], accZ[4*g+1], accZ[4*g+2], accZ[4*g+3]};
    *(float4*)&zrow[d0 + 4 * g] = zv;
  }
}

// ---------- state scan: S_{c+1} = P_c S_c + Z_c; Sbuf transposed [ch][j][d] ----------
__global__ __launch_bounds__(256) void state_kernel(
    const float* __restrict__ kn /*Zt*/, const float* __restrict__ Pbuf /*slot-major*/,
    float* __restrict__ Sbuf) {
  __shared__ __align__(16) float Pl[2][4096];
  int bid = blockIdx.x;
  int bh = bid & 31, js = bid >> 5;
  int h = bh & 15, b = bh >> 4;
  int tid = threadIdx.x;
  int wv = tid >> 6, lane = tid & 63;   // lane = d
  int j0 = js * 4 + wv;                 // this wave's column
  float s0 = 0.f;
  const size_t bhNC = (size_t)bh * NC_;
  const float* Pg0 = Pbuf + bhNC * 4096;
  #pragma unroll
  for (int g = 0; g < 4; g++)
    __builtin_amdgcn_global_load_lds(
        (const __attribute__((address_space(1))) void*)(Pg0 + (g * 256 + tid) * 4),
        (__attribute__((address_space(3))) void*)&Pl[0][(g * 256 + tid) * 4], 16, 0, 0);
  float zn = kn[((size_t)(b * T_ + j0)) * D_ + h * 64 + lane];
  int cur = 0;
  #pragma unroll 1
  for (int c = 0; c < NC_; c++) {
    __syncthreads();            // implies vmcnt(0) drain: buf[cur] ready for all waves
    float z = zn;
    size_t ch = bhNC + c;
    if (c + 1 < NC_) {
      const float* Pg = Pbuf + (ch + 1) * 4096;
      #pragma unroll
      for (int g = 0; g < 4; g++)
        __builtin_amdgcn_global_load_lds(
            (const __attribute__((address_space(1))) void*)(Pg + (g * 256 + tid) * 4),
            (__attribute__((address_space(3))) void*)&Pl[cur ^ 1][(g * 256 + tid) * 4], 16, 0, 0);
      zn = kn[((size_t)(b * T_ + (c + 1) * 64 + j0)) * D_ + h * 64 + lane];
    }
    Sbuf[ch * 4096 + (size_t)j0 * 64 + lane] = s0;
    float acc = z;
    #pragma unroll
    for (int f = 0; f < 16; f++) {
      floatx4 pv = *(floatx4*)&Pl[cur][f * 256 + lane * 4];
      acc += pv.x * rdlane(s0, f * 4 + 0);
      acc += pv.y * rdlane(s0, f * 4 + 1);
      acc += pv.z * rdlane(s0, f * 4 + 2);
      acc += pv.w * rdlane(s0, f * 4 + 3);
    }
    s0 = acc;
    cur ^= 1;
  }
}

// ---------- O = O0 + Qeff*S_c (S transposed layout), fused RMSNorm + bf16 cast ----------
__global__ __launch_bounds__(256) void ophase_kernel(
    const float* __restrict__ qn /*Qeff*/, const float* __restrict__ Sbuf,
    const float* __restrict__ O0buf, const float* __restrict__ rms_g,
    ushort* __restrict__ ob) {
  __shared__ float Ssht[64][68];
  __shared__ float QshT[64][65];
  __shared__ float part[64][4];
  int ch = blockIdx.x;
  int b = ch >> 9, h = (ch >> 5) & 15, c = ch & 31;
  int tid = threadIdx.x;
  int t = tid & 63, jg = tid >> 6;
  #pragma unroll
  for (int g = 0; g < 4; g++) {
    int idx = tid + g * 256;
    *(float4*)&Ssht[idx >> 4][(idx & 15) * 4] =
        *(const float4*)&Sbuf[(size_t)ch * 4096 + (size_t)idx * 4];
  }
  #pragma unroll
  for (int g = 0; g < 4; g++) {
    int idx = tid + g * 256;
    int row = idx >> 4, c4 = idx & 15;
    float4 qv = *(const float4*)&qn[((size_t)(b * T_ + c * 64 + row)) * D_ + h * 64 + c4 * 4];
    QshT[c4 * 4 + 0][row] = qv.x;
    QshT[c4 * 4 + 1][row] = qv.y;
    QshT[c4 * 4 + 2][row] = qv.z;
    QshT[c4 * 4 + 3][row] = qv.w;
  }
  float o[16];
  #pragma unroll
  for (int g = 0; g < 4; g++) {
    float4 o4 = *(const float4*)&O0buf[(size_t)ch * 4096 + t * 64 + jg * 16 + g * 4];
    o[4*g+0] = o4.x; o[4*g+1] = o4.y; o[4*g+2] = o4.z; o[4*g+3] = o4.w;
  }
  __syncthreads();
  for (int d4 = 0; d4 < 16; d4++) {
    float q0 = QshT[d4 * 4 + 0][t];
    float q1 = QshT[d4 * 4 + 1][t];
    float q2 = QshT[d4 * 4 + 2][t];
    float q3 = QshT[d4 * 4 + 3][t];
    #pragma unroll
    for (int r = 0; r < 16; r++) {
      float4 s4 = *(float4*)&Ssht[jg * 16 + r][d4 * 4];
      o[r] += q0 * s4.x + q1 * s4.y + q2 * s4.z + q3 * s4.w;
    }
  }
  float ss = 0.f;
  #pragma unroll
  for (int r = 0; r < 16; r++) ss += o[r] * o[r];
  part[t][jg] = ss;
  __syncthreads();
  float tot = part[t][0] + part[t][1] + part[t][2] + part[t][3];
  float sc = rsqrtf(tot * (1.f / 64.f) + 1e-6f);
  ushort* orow = &ob[((size_t)(b * T_ + c * 64 + t)) * D_ + h * 64];
  #pragma unroll
  for (int g = 0; g < 4; g++) {
    float4 g4 = *(const float4*)&rms_g[jg * 16 + g * 4];
    ushort4 r4;
    r4.x = f2bf(o[4*g+0] * sc * g4.x); r4.y = f2bf(o[4*g+1] * sc * g4.y);
    r4.z = f2bf(o[4*g+2] * sc * g4.z); r4.w = f2bf(o[4*g+3] * sc * g4.w);
    *(ushort4*)&orow[jg * 16 + g * 4] = r4;
  }
}

extern "C" void kernel_launch(void* const* d_in, const int* in_sizes, int n_in,
                              void* d_out, int out_size, void* d_ws, size_t ws_size,
                              hipStream_t stream) {
  const float* x  = (const float*)d_in[0];
  const float* Wq = (const float*)d_in[1];
  const float* Wk = (const float*)d_in[2];
  const float* Wv = (const float*)d_in[3];
  const float* Wb = (const float*)d_in[4];
  const float* cq = (const float*)d_in[5];
  const float* ck = (const float*)d_in[6];
  const float* cv = (const float*)d_in[7];
  const float* rg = (const float*)d_in[8];
  const float* Wo = (const float*)d_in[9];
  float* out = (float*)d_out;
  char* ws = (char*)d_ws;
  const size_t MiB = 1ull << 20;
  ushort* xb   = (ushort*)(ws + 0);         // dead after QKV gemm
  ushort* Wqt  = (ushort*)(ws + 8 * MiB);   // Wqt/Wkt/Wvt contiguous = [3072][1024] bf16
  ushort* Wkt  = (ushort*)(ws + 10 * MiB);
  ushort* Wvt  = (ushort*)(ws + 12 * MiB);
  ushort* Wot  = (ushort*)(ws + 14 * MiB);  // live to end
  float* qkv   = (float*)(ws + 16 * MiB);   // [4096][3072] fp32, dead after conv
  float* qn    = (float*)(ws + 64 * MiB);   // then Qeff in-place
  float* kn    = (float*)(ws + 80 * MiB);   // then Zt in-place
  float* vn    = (float*)(ws + 96 * MiB);   // dead after prep1
  float* beta  = (float*)(ws + 112 * MiB);  // 256 KiB
  float* WbT   = (float*)(ws + 112 * MiB + 256 * 1024);  // 64 KiB
  float* Wkbuf = (float*)(ws + 16 * MiB);   // over qkv (dead after conv)
  float* U0buf = (float*)(ws + 32 * MiB);
  float* Pbuf  = (float*)(ws + 48 * MiB);   // P (prep2c out, state in)
  float* O0buf = (float*)(ws + 96 * MiB);   // over vn (after prep1)
  float* Sbuf  = (float*)(ws + 16 * MiB);   // over Wkbuf (dead after prep2c)
  ushort* ob   = (ushort*)(ws + 0);         // over xb (after QKV gemm)

  hipLaunchKernelGGL(cast_kernel, dim3(M_ * D_ / 4 / 256), dim3(256), 0, stream,
                     x, xb, M_ * D_ / 4);
  dim3 tb(32, 8);
  hipLaunchKernelGGL(transpose_cast_kernel, dim3(32, 32), tb, 0, stream, Wq, Wqt, D_, D_);
  hipLaunchKernelGGL(transpose_cast_kernel, dim3(32, 32), tb, 0, stream, Wk, Wkt, D_, D_);
  hipLaunchKernelGGL(transpose_cast_kernel, dim3(32, 32), tb, 0, stream, Wv, Wvt, D_, D_);
  hipLaunchKernelGGL(transpose_cast_kernel, dim3(32, 32), tb, 0, stream, Wo, Wot, D_, D_);
  hipLaunchKernelGGL(transpose_wb_kernel, dim3(64), dim3(256), 0, stream, Wb, WbT);

  hipLaunchKernelGGL(gemm128_kernel, dim3(M_ / 128, QKVN_ / 128), dim3(256), 0, stream,
                     xb, Wqt, qkv, M_, QKVN_, D_);

  hipLaunchKernelGGL(beta_kernel, dim3(M_ / 16), dim3(256), 0, stream, x, WbT, beta);
  hipLaunchKernelGGL(conv_kernel, dim3(M_), dim3(256), 0, stream,
                     qkv, cq, ck, cv, qn, kn, vn);

  hipLaunchKernelGGL(prep1_kernel, dim3(NCH_), dim3(256), 0, stream,
                     kn, vn, beta, Wkbuf, U0buf);
  hipLaunchKernelGGL(prep2ab_kernel, dim3(NCH_), dim3(256), 0, stream,
                     qn, kn, Wkbuf, U0buf, O0buf);
  hipLaunchKernelGGL(prep2c_kernel, dim3(NCH_), dim3(256), 0, stream,
                     kn, Wkbuf, U0buf, Pbuf);
  hipLaunchKernelGGL(state_kernel, dim3(512), dim3(256), 0, stream,
                     kn, Pbuf, Sbuf);
  hipLaunchKernelGGL(ophase_kernel, dim3(NCH_), dim3(256), 0, stream,
                     qn, Sbuf, O0buf, rg, ob);
  hipLaunchKernelGGL(gemm128_kernel, dim3(M_ / 128, D_ / 128), dim3(256), 0, stream,
                     ob, Wot, out, M_, D_, D_);
}

// Round 13
// 345.369 us; speedup vs baseline: 1.0988x; 1.0361x over previous
//
#include <hip/hip_runtime.h>
#include <hip/hip_bf16.h>
#include <math.h>

#define B_ 2
#define T_ 2048
#define D_ 1024
#define H_ 16
#define DH_ 64
#define M_ (B_*T_)   // 4096 rows
#define NC_ 32       // chunks per sequence (T/64)
#define CS_ 64       // chunk size
#define NCH_ (B_*H_*NC_)  // 1024 chunk-heads
#define QKVN_ 3072   // fused QKV gemm N

typedef __attribute__((ext_vector_type(4))) float floatx4;
typedef __attribute__((ext_vector_type(8))) short short8;

__device__ __forceinline__ ushort f2bf(float f) {
  union { float f; unsigned u; } c; c.f = f;
  unsigned r = (c.u + 0x7FFFu + ((c.u >> 16) & 1u)) >> 16;  // RNE
  return (ushort)r;
}
__device__ __forceinline__ float siluf(float u) {
  return u / (1.f + __expf(-u));
}
__device__ __forceinline__ float f4get(const float4& v, int j) {
  return j == 0 ? v.x : j == 1 ? v.y : j == 2 ? v.z : v.w;
}
__device__ __forceinline__ float rdlane(float v, int l) {
  return __int_as_float(__builtin_amdgcn_readlane(__float_as_int(v), l));
}
// swizzled chunk index for K tiles: chunk c (0..15) of row r stored at c ^ (r>>4)
__device__ __forceinline__ int ksw(int r, int c) { return ((c ^ (r >> 4)) << 2); }

// ---------- cast f32 -> bf16, n4 = n/4 ----------
__global__ void cast_kernel(const float* __restrict__ in, ushort* __restrict__ out, int n4) {
  int i = blockIdx.x * blockDim.x + threadIdx.x;
  if (i >= n4) return;
  float4 v = ((const float4*)in)[i];
  ushort4 o;
  o.x = f2bf(v.x); o.y = f2bf(v.y); o.z = f2bf(v.z); o.w = f2bf(v.w);
  ((ushort4*)out)[i] = o;
}

// ---------- transpose + cast x4 weights in one launch: W[1024][1024] f32 -> Wt bf16 ----------
__global__ void transpose_cast4_kernel(
    const float* __restrict__ W0, const float* __restrict__ W1,
    const float* __restrict__ W2, const float* __restrict__ W3,
    ushort* __restrict__ T0, ushort* __restrict__ T1,
    ushort* __restrict__ T2, ushort* __restrict__ T3) {
  __shared__ float tile[32][33];
  int z = blockIdx.z;
  const float* W = z == 0 ? W0 : z == 1 ? W1 : z == 2 ? W2 : W3;
  ushort* Wt = z == 0 ? T0 : z == 1 ? T1 : z == 2 ? T2 : T3;
  int tx = threadIdx.x, ty = threadIdx.y;
  int n0 = blockIdx.x * 32, k0 = blockIdx.y * 32;
  #pragma unroll
  for (int i = 0; i < 32; i += 8)
    tile[ty + i][tx] = W[(size_t)(k0 + ty + i) * D_ + n0 + tx];
  __syncthreads();
  #pragma unroll
  for (int i = 0; i < 32; i += 8)
    Wt[(size_t)(n0 + ty + i) * D_ + k0 + tx] = f2bf(tile[tx][ty + i]);
}

// ---------- transpose Wb[1024][16] -> WbT[16][1024] (fp32) ----------
__global__ void transpose_wb_kernel(const float* __restrict__ Wb, float* __restrict__ WbT) {
  int bk = blockIdx.x;
  int tid = threadIdx.x;
  int kl = tid >> 4, h = tid & 15;
  int k = bk * 16 + kl;
  WbT[(size_t)h * D_ + k] = Wb[(size_t)k * H_ + h];
}

// ---------- bf16 MFMA GEMM, 2-phase counted-vmcnt pipeline + XCD supertile swizzle ----------
__global__ __launch_bounds__(256) void gemm128_kernel(
    const ushort* __restrict__ A, const ushort* __restrict__ Bt,
    float* __restrict__ C, int M, int N, int K) {
  __shared__ ushort lA[2][128 * 32];
  __shared__ ushort lB[2][128 * 32];
  int tid = threadIdx.x;
  int wave = tid >> 6, lane = tid & 63;
  int wm = wave >> 1, wn = wave & 1;
  int m16 = lane & 15, q4 = lane >> 4;
  // XCD-aware bijective swizzle with 8x8 supertiles
  int nbm = gridDim.x, nbn = gridDim.y;
  int lin = blockIdx.y * nbm + blockIdx.x;
  int cpx = (nbm * nbn) >> 3;
  int swz = (lin & 7) * cpx + (lin >> 3);
  int stn = nbn >> 3;
  int st = swz >> 6, in_ = swz & 63;
  int stm = st / stn, soff = st - stm * stn;
  int bm = stm * 8 + (in_ & 7);
  int bn = soff * 8 + (in_ >> 3);
  floatx4 acc[4][4] = {};
  int srow = tid >> 2;
  int sk8 = tid & 3;
  const ushort* Ag = A + (size_t)(bm * 128 + srow) * K + sk8 * 8;
  const ushort* Bg = Bt + (size_t)(bn * 128 + srow) * K + sk8 * 8;
  int nks = K >> 5;

#define GSTAGE(bufi, kk0)                                                       \
  {                                                                             \
    __builtin_amdgcn_global_load_lds(                                           \
        (const __attribute__((address_space(1))) void*)(Ag + (kk0)),            \
        (__attribute__((address_space(3))) void*)&lA[bufi][tid * 8], 16, 0, 0); \
    __builtin_amdgcn_global_load_lds(                                           \
        (const __attribute__((address_space(1))) void*)(Ag + (size_t)64 * K + (kk0)), \
        (__attribute__((address_space(3))) void*)&lA[bufi][tid * 8 + 2048], 16, 0, 0); \
    __builtin_amdgcn_global_load_lds(                                           \
        (const __attribute__((address_space(1))) void*)(Bg + (kk0)),            \
        (__attribute__((address_space(3))) void*)&lB[bufi][tid * 8], 16, 0, 0); \
    __builtin_amdgcn_global_load_lds(                                           \
        (const __attribute__((address_space(1))) void*)(Bg + (size_t)64 * K + (kk0)), \
        (__attribute__((address_space(3))) void*)&lB[bufi][tid * 8 + 2048], 16, 0, 0); \
  }

  GSTAGE(0, 0);
  int cur = 0;
  #pragma unroll 1
  for (int ks = 0; ks < nks; ++ks) {
    if (ks + 1 < nks) {
      GSTAGE(cur ^ 1, (ks + 1) * 32);
      asm volatile("s_waitcnt vmcnt(4)" ::: "memory");
    } else {
      asm volatile("s_waitcnt vmcnt(0)" ::: "memory");
    }
    __builtin_amdgcn_s_barrier();       // buf[cur] staged & visible
    __builtin_amdgcn_sched_barrier(0);
    short8 af[4], bf[4];
    #pragma unroll
    for (int i = 0; i < 4; i++) {
      af[i] = *(short8*)&lA[cur][(wm * 64 + i * 16 + m16) * 32 + q4 * 8];
      bf[i] = *(short8*)&lB[cur][(wn * 64 + i * 16 + m16) * 32 + q4 * 8];
    }
    #pragma unroll
    for (int mi = 0; mi < 4; mi++)
      #pragma unroll
      for (int nj = 0; nj < 4; nj++)
        acc[mi][nj] = __builtin_amdgcn_mfma_f32_16x16x32_bf16(af[mi], bf[nj], acc[mi][nj], 0, 0, 0);
    __builtin_amdgcn_s_barrier();       // all waves done reading buf[cur]
    cur ^= 1;
  }
#undef GSTAGE
  float* Cb = C + (size_t)(bm * 128) * N + bn * 128;
  #pragma unroll
  for (int mi = 0; mi < 4; mi++) {
    #pragma unroll
    for (int nj = 0; nj < 4; nj++) {
      #pragma unroll
      for (int i = 0; i < 4; i++) {
        int row = wm * 64 + mi * 16 + q4 * 4 + i;
        int col = wn * 64 + nj * 16 + m16;
        Cb[(size_t)row * N + col] = acc[mi][nj][i];
      }
    }
  }
}

// ---------- beta = sigmoid(x @ Wb): blocked GEMV, 16 rows/block ----------
__global__ __launch_bounds__(256) void beta_kernel(const float* __restrict__ x,
                                                   const float* __restrict__ WbT,
                                                   float* __restrict__ beta) {
  __shared__ __align__(16) float4 wsh[16][256];   // 64 KB
  int tid = threadIdx.x;
  const float4* Wb4 = (const float4*)WbT;
  #pragma unroll
  for (int i = 0; i < 16; i++) {
    int idx = i * 256 + tid;
    int h = idx >> 8, c = idx & 255;
    wsh[h][c ^ (h & 7)] = Wb4[h * 256 + c];
  }
  __syncthreads();
  int r = tid >> 4, h = tid & 15;
  int hs = h & 7;
  int row = blockIdx.x * 16 + r;
  const float4* xr = (const float4*)(x + (size_t)row * D_);
  float acc0 = 0.f, acc1 = 0.f, acc2 = 0.f, acc3 = 0.f;
  #pragma unroll 8
  for (int c = 0; c < 256; c += 4) {
    float4 x0 = xr[c + 0], x1 = xr[c + 1], x2 = xr[c + 2], x3 = xr[c + 3];
    float4 w0 = wsh[h][(c + 0) ^ hs];
    float4 w1 = wsh[h][(c + 1) ^ hs];
    float4 w2 = wsh[h][(c + 2) ^ hs];
    float4 w3 = wsh[h][(c + 3) ^ hs];
    acc0 += x0.x * w0.x + x0.y * w0.y + x0.z * w0.z + x0.w * w0.w;
    acc1 += x1.x * w1.x + x1.y * w1.y + x1.z * w1.z + x1.w * w1.w;
    acc2 += x2.x * w2.x + x2.y * w2.y + x2.z * w2.z + x2.w * w2.w;
    acc3 += x3.x * w3.x + x3.y * w3.y + x3.z * w3.z + x3.w * w3.w;
  }
  float s = (acc0 + acc1) + (acc2 + acc3);
  beta[(size_t)row * H_ + h] = 1.f / (1.f + __expf(-s));
}

// ---------- causal depthwise conv(K=4) + silu, l2norm for q,k ----------
__global__ __launch_bounds__(256) void conv_kernel(
    const float* __restrict__ qkv,
    const float* __restrict__ cq, const float* __restrict__ ck, const float* __restrict__ cv,
    float* __restrict__ qo, float* __restrict__ ko, float* __restrict__ vo) {
  int row = blockIdx.x;
  int t = row & (T_ - 1);
  int tid = threadIdx.x;
  int c0 = tid * 4;
  float4 zf = {0.f, 0.f, 0.f, 0.f};
  float4 xq[4], xk[4], xv[4];
  #pragma unroll
  for (int i = 0; i < 4; i++) {
    int tt = t - 3 + i;
    if (tt >= 0) {
      const float* rp = qkv + (size_t)(row - 3 + i) * QKVN_;
      xq[i] = *(const float4*)(rp + c0);
      xk[i] = *(const float4*)(rp + 1024 + c0);
      xv[i] = *(const float4*)(rp + 2048 + c0);
    } else { xq[i] = zf; xk[i] = zf; xv[i] = zf; }
  }
  float yq[4], yk[4], yv[4];
  float pq = 0.f, pk = 0.f;
  #pragma unroll
  for (int j = 0; j < 4; j++) {
    float4 wq = ((const float4*)cq)[c0 + j];
    float4 wk = ((const float4*)ck)[c0 + j];
    float4 wv = ((const float4*)cv)[c0 + j];
    float sq = 0.f, sk = 0.f, sv = 0.f;
    #pragma unroll
    for (int i = 0; i < 4; i++) {
      sq += f4get(wq, i) * f4get(xq[i], j);
      sk += f4get(wk, i) * f4get(xk[i], j);
      sv += f4get(wv, i) * f4get(xv[i], j);
    }
    yq[j] = siluf(sq); yk[j] = siluf(sk); yv[j] = siluf(sv);
    pq += yq[j] * yq[j]; pk += yk[j] * yk[j];
  }
  #pragma unroll
  for (int off = 1; off < 16; off <<= 1) {
    pq += __shfl_xor(pq, off, 16);
    pk += __shfl_xor(pk, off, 16);
  }
  float rq = rsqrtf(pq + 1e-6f), rk = rsqrtf(pk + 1e-6f);
  float4 oq = {yq[0]*rq, yq[1]*rq, yq[2]*rq, yq[3]*rq};
  float4 okk = {yk[0]*rk, yk[1]*rk, yk[2]*rk, yk[3]*rk};
  float4 ov = {yv[0], yv[1], yv[2], yv[3]};
  *(float4*)(qo + (size_t)row * D_ + c0) = oq;
  *(float4*)(ko + (size_t)row * D_ + c0) = okk;
  *(float4*)(vo + (size_t)row * D_ + c0) = ov;
}

// ================= chunked delta rule =================
// prep1: A = strict_tril(diag(b)KK^T); solve (I+A)Wk = diag(b)K and (I+A)U0 = diag(b)V
// A-phase via split-bf16 MFMA (hi/lo split in staging loop; bank-staggered LDS,
// XOR-16 involution on write and read). Solve phases R3-verified.
__global__ __launch_bounds__(256) void prep1_kernel(
    const float* __restrict__ kn, const float* __restrict__ vn,
    const float* __restrict__ beta,
    float* __restrict__ Wkbuf, float* __restrict__ U0buf) {
  __shared__ __align__(16) float Ash[64 * 68];   // A[t][s] row-major, stride 68
  __shared__ float bsh[64];
  __shared__ __align__(16) float uni[5312];
  ushort* KH = (ushort*)uni;                                // 64 rows x 160B = 10240B
  ushort* KL = (ushort*)uni + 5120;                         // next 10240B
  float (*Tsh)[16][20] = (float (*)[16][20])uni;            // [4][16][20] = 1280
  float (*Msh)[16][20] = (float (*)[16][20])(uni + 1280);   // [6][16][20] = 1920
  float (*Xsh)[132] = (float (*)[132])(uni + 3200);         // [16][132]  = 2112

  int ch = blockIdx.x;
  int b = ch >> 9, h = (ch >> 5) & 15, c = ch & 31;
  int tid = threadIdx.x;
  int t = tid >> 2, seg = tid & 3;
  int wave = tid >> 6, lane = tid & 63;
  int r = lane >> 2, q = lane & 3;   // r == t&15, q == seg
  int m16 = lane & 15, oct = lane >> 4;
  const float* kg = kn + ((size_t)(b * T_ + c * 64)) * D_ + h * 64;
  {
    #pragma unroll
    for (int p = 0; p < 2; p++) {
      int idx = p * 256 + tid;          // 16B dest unit
      int row = idx >> 3, cb = (idx & 7) * 16;
      int scb = cb ^ ((row & 7) << 4);  // source byte col (bf16 units)
      const float* src = kg + (size_t)row * D_ + (scb >> 1);
      float4 va = *(const float4*)src;
      float4 vb = *(const float4*)(src + 4);
      float v[8] = {va.x, va.y, va.z, va.w, vb.x, vb.y, vb.z, vb.w};
      short8 hi8, lo8;
      #pragma unroll
      for (int j = 0; j < 8; j++) {
        unsigned u = __float_as_uint(v[j]);
        hi8[j] = (short)(u >> 16);                      // truncated bf16 hi
        lo8[j] = (short)f2bf(v[j] - __uint_as_float(u & 0xFFFF0000u));
      }
      *(short8*)((char*)KH + row * 160 + cb) = hi8;
      *(short8*)((char*)KL + row * 160 + cb) = lo8;
    }
  }
  if (tid < 64) bsh[tid] = beta[((size_t)(b * T_ + c * 64 + tid)) * H_ + h];
  __syncthreads();
  // A[t][s] = (t>s) ? b_t * (k_t . k_s) : 0 — split-bf16 MFMA; wave w owns row-tile w
  {
    floatx4 acc[4] = {};
    #pragma unroll
    for (int ks = 0; ks < 2; ks++) {
      int ob = (ks * 64 + oct * 16) ^ ((m16 & 7) << 4);
      short8 fah = *(short8*)((char*)KH + (wave * 16 + m16) * 160 + ob);
      short8 fal = *(short8*)((char*)KL + (wave * 16 + m16) * 160 + ob);
      #pragma unroll
      for (int si = 0; si < 4; si++) {
        short8 fbh = *(short8*)((char*)KH + (si * 16 + m16) * 160 + ob);
        short8 fbl = *(short8*)((char*)KL + (si * 16 + m16) * 160 + ob);
        acc[si] = __builtin_amdgcn_mfma_f32_16x16x32_bf16(fah, fbh, acc[si], 0, 0, 0);
        acc[si] = __builtin_amdgcn_mfma_f32_16x16x32_bf16(fah, fbl, acc[si], 0, 0, 0);
        acc[si] = __builtin_amdgcn_mfma_f32_16x16x32_bf16(fal, fbh, acc[si], 0, 0, 0);
      }
    }
    #pragma unroll
    for (int si = 0; si < 4; si++) {
      #pragma unroll
      for (int rr = 0; rr < 4; rr++) {
        int row = wave * 16 + oct * 4 + rr;
        int col = si * 16 + m16;
        float bt = bsh[row];
        Ash[row * 68 + col] = (row > col) ? bt * acc[si][rr] : 0.f;
      }
    }
  }
  // RHS (residual Y) in registers: row t, 16 K-cols + 16 V-cols (fp32 from global)
  float xk[16], xv[16];
  {
    float bt = bsh[t];
    const float* krow = kn + ((size_t)(b * T_ + c * 64 + t)) * D_ + h * 64;
    const float* vrow = vn + ((size_t)(b * T_ + c * 64 + t)) * D_ + h * 64;
    #pragma unroll
    for (int g = 0; g < 4; g++) {
      float4 kv = *(const float4*)&krow[seg * 16 + 4 * g];
      float4 vv = *(const float4*)&vrow[seg * 16 + 4 * g];
      xk[4*g+0] = bt * kv.x; xk[4*g+1] = bt * kv.y; xk[4*g+2] = bt * kv.z; xk[4*g+3] = bt * kv.w;
      xv[4*g+0] = bt * vv.x; xv[4*g+1] = bt * vv.y; xv[4*g+2] = bt * vv.z; xv[4*g+3] = bt * vv.w;
    }
  }
  __syncthreads();   // Ash ready; KH/KL dead -> Tsh/Msh/Xsh region live
  // Phase A: wave-parallel 16x16 diagonal-block inverse via fwd substitution on I
  {
    float a[16];
    #pragma unroll
    for (int i = 0; i < 16; i++) a[i] = Ash[(wave * 16 + r) * 68 + wave * 16 + i];
    float4 w4 = {0.f, 0.f, 0.f, 0.f};
    if ((r >> 2) == q) ((float*)&w4)[r & 3] = 1.f;
    #pragma unroll
    for (int i = 0; i < 15; i++) {
      int src = i * 4 + q;
      float4 wi;
      wi.x = __shfl(w4.x, src, 64);
      wi.y = __shfl(w4.y, src, 64);
      wi.z = __shfl(w4.z, src, 64);
      wi.w = __shfl(w4.w, src, 64);
      if (r > i) {
        w4.x -= a[i] * wi.x; w4.y -= a[i] * wi.y;
        w4.z -= a[i] * wi.z; w4.w -= a[i] * wi.w;
      }
    }
    *(float4*)&Tsh[wave][r][q * 4] = w4;
  }
  __syncthreads();   // Tsh visible to all waves
  // Phase B: M_wk = A_wk * T_kk (wave-local write, wave-local read)
  for (int k = 0; k < wave; k++) {
    float4 m4 = {0.f, 0.f, 0.f, 0.f};
    #pragma unroll
    for (int i = 0; i < 16; i++) {
      float aik = Ash[(wave * 16 + r) * 68 + k * 16 + i];
      float4 tk = *(float4*)&Tsh[k][i][q * 4];
      m4.x += aik * tk.x; m4.y += aik * tk.y;
      m4.z += aik * tk.z; m4.w += aik * tk.w;
    }
    int mi = wave * (wave - 1) / 2 + k;
    *(float4*)&Msh[mi][r][q * 4] = m4;
  }
  // Block substitution k-loop
  float* wkout = &Wkbuf[(size_t)ch * 4096 + t * 64];
  float* u0out = &U0buf[(size_t)ch * 4096 + t * 64];
  for (int k = 0; k < 4; k++) {
    if (wave == k) {   // publish residual Y_k
      #pragma unroll
      for (int g = 0; g < 4; g++) {
        float4 k4 = {xk[4*g+0], xk[4*g+1], xk[4*g+2], xk[4*g+3]};
        float4 v4 = {xv[4*g+0], xv[4*g+1], xv[4*g+2], xv[4*g+3]};
        *(float4*)&Xsh[r][seg * 16 + 4 * g] = k4;
        *(float4*)&Xsh[r][64 + seg * 16 + 4 * g] = v4;
      }
    }
    __syncthreads();
    if (wave == k) {
      // X_k = T_kk * Y_k -> final output, straight to global
      float nk[16], nv[16];
      #pragma unroll
      for (int i2 = 0; i2 < 16; i2++) { nk[i2] = 0.f; nv[i2] = 0.f; }
      #pragma unroll
      for (int i = 0; i < 16; i++) {
        float tc = Tsh[k][r][i];
        #pragma unroll
        for (int g = 0; g < 4; g++) {
          float4 yk = *(float4*)&Xsh[i][seg * 16 + 4 * g];
          float4 yv = *(float4*)&Xsh[i][64 + seg * 16 + 4 * g];
          nk[4*g+0] += tc * yk.x; nk[4*g+1] += tc * yk.y;
          nk[4*g+2] += tc * yk.z; nk[4*g+3] += tc * yk.w;
          nv[4*g+0] += tc * yv.x; nv[4*g+1] += tc * yv.y;
          nv[4*g+2] += tc * yv.z; nv[4*g+3] += tc * yv.w;
        }
      }
      #pragma unroll
      for (int g = 0; g < 4; g++) {
        float4 k4 = {nk[4*g+0], nk[4*g+1], nk[4*g+2], nk[4*g+3]};
        float4 v4 = {nv[4*g+0], nv[4*g+1], nv[4*g+2], nv[4*g+3]};
        *(float4*)&wkout[seg * 16 + 4 * g] = k4;
        *(float4*)&u0out[seg * 16 + 4 * g] = v4;
      }
    } else if (wave > k) {
      // Y_i -= M_ik * Y_k   (== A_ik * X_k)
      int mi = wave * (wave - 1) / 2 + k;
      #pragma unroll
      for (int i = 0; i < 16; i++) {
        float mc = Msh[mi][r][i];
        #pragma unroll
        for (int g = 0; g < 4; g++) {
          float4 yk = *(float4*)&Xsh[i][seg * 16 + 4 * g];
          float4 yv = *(float4*)&Xsh[i][64 + seg * 16 + 4 * g];
          xk[4*g+0] -= mc * yk.x; xk[4*g+1] -= mc * yk.y;
          xk[4*g+2] -= mc * yk.z; xk[4*g+3] -= mc * yk.w;
          xv[4*g+0] -= mc * yv.x; xv[4*g+1] -= mc * yv.y;
          xv[4*g+2] -= mc * yv.z; xv[4*g+3] -= mc * yv.w;
        }
      }
    }
    __syncthreads();
  }
}

// prep2abc: fused prep2a+prep2b+prep2c. ONE staging pass (Q, K-swizzled, Wk, U0
// all resident; 68KB LDS, 2 blocks/CU):
//   phase 1: L = tril(Q K^T) in regs (4x4 tile) -> overwrite dead Q buffer with L
//   phase 2: O0 = L U0 ; Qeff = Q - L Wk (Q re-read from global in epilogue)
//   phase 3 (no barrier needed - reads only staging-resident Ksh/Wksh/U0sh):
//            P[d][e] = I - (K^T Wk), slot-major -> Pbuf; Zt = (U0^T K) -> kn
// Saves prep2c's 48MB re-staging + one launch. All arithmetic order identical.
__global__ __launch_bounds__(256) void prep2abc_kernel(
    float* qn, float* kn,
    const float* __restrict__ Wkbuf, const float* __restrict__ U0buf,
    float* __restrict__ O0buf, float* __restrict__ Pbuf) {
  __shared__ float Ash[64][68];   // Q, then L
  __shared__ float Ksh[64][68];   // swizzled K (persistent)
  __shared__ float Wksh[64][68];  // persistent
  __shared__ float U0sh[64][68];  // persistent
  int ch = blockIdx.x;
  int b = ch >> 9, h = (ch >> 5) & 15, c = ch & 31;
  int tid = threadIdx.x;
  int t = tid >> 2, seg = tid & 3;
  const float* qrow = qn + ((size_t)(b * T_ + c * 64 + t)) * D_ + h * 64;
  const float* krow = kn + ((size_t)(b * T_ + c * 64 + t)) * D_ + h * 64;
  #pragma unroll
  for (int g = 0; g < 4; g++) {
    int o = t * 64 + seg * 16 + 4 * g;
    *(float4*)&Ash[t][seg * 16 + 4 * g] = *(const float4*)&qrow[seg * 16 + 4 * g];
    *(float4*)&Ksh[t][ksw(t, seg * 4 + g)] = *(const float4*)&krow[seg * 16 + 4 * g];
    *(float4*)&Wksh[t][seg * 16 + 4 * g] = *(const float4*)&Wkbuf[(size_t)ch * 4096 + o];
    *(float4*)&U0sh[t][seg * 16 + 4 * g] = *(const float4*)&U0buf[(size_t)ch * 4096 + o];
  }
  __syncthreads();
  // phase 1: L = tril(Q K^T), 4x4 register tile per thread (Q read from Ash)
  float accL[4][4];
  int qt = tid >> 4, qs = tid & 15;
  {
    int sws = qs >> 2;
    #pragma unroll
    for (int i = 0; i < 4; i++)
      #pragma unroll
      for (int j = 0; j < 4; j++) accL[i][j] = 0.f;
    for (int d4 = 0; d4 < 16; d4++) {
      float4 qv[4], ks[4];
      #pragma unroll
      for (int i = 0; i < 4; i++) qv[i] = *(float4*)&Ash[qt * 4 + i][d4 * 4];
      #pragma unroll
      for (int j = 0; j < 4; j++) ks[j] = *(float4*)&Ksh[qs * 4 + j][((d4 ^ sws) << 2)];
      #pragma unroll
      for (int i = 0; i < 4; i++)
        #pragma unroll
        for (int j = 0; j < 4; j++)
          accL[i][j] += qv[i].x * ks[j].x + qv[i].y * ks[j].y
                      + qv[i].z * ks[j].z + qv[i].w * ks[j].w;
    }
  }
  __syncthreads();   // all Q reads done; Ash may be overwritten with L
  #pragma unroll
  for (int i = 0; i < 4; i++) {
    int row = qt * 4 + i;
    float4 ov;
    ov.x = (qs * 4 + 0 <= row) ? accL[i][0] : 0.f;
    ov.y = (qs * 4 + 1 <= row) ? accL[i][1] : 0.f;
    ov.z = (qs * 4 + 2 <= row) ? accL[i][2] : 0.f;
    ov.w = (qs * 4 + 3 <= row) ? accL[i][3] : 0.f;
    *(float4*)&Ash[row][qs * 4] = ov;
  }
  __syncthreads();   // L visible
  // phase 2: O0 = L U0 ; Qeff = Q - L Wk (identical arithmetic to old prep2b)
  {
    int j0 = seg * 16;
    float o0[16], lw[16];
    #pragma unroll
    for (int r = 0; r < 16; r++) { o0[r] = 0.f; lw[r] = 0.f; }
    for (int s = 0; s <= t; s++) {
      float l = Ash[t][s];
      #pragma unroll
      for (int g = 0; g < 4; g++) {
        float4 u = *(float4*)&U0sh[s][j0 + 4 * g];
        float4 w = *(float4*)&Wksh[s][j0 + 4 * g];
        o0[4*g+0] += l * u.x; o0[4*g+1] += l * u.y; o0[4*g+2] += l * u.z; o0[4*g+3] += l * u.w;
        lw[4*g+0] += l * w.x; lw[4*g+1] += l * w.y; lw[4*g+2] += l * w.z; lw[4*g+3] += l * w.w;
      }
    }
    float* qwrow = qn + ((size_t)(b * T_ + c * 64 + t)) * D_ + h * 64;
    #pragma unroll
    for (int g = 0; g < 4; g++) {
      float4 qv = *(const float4*)&qwrow[j0 + 4 * g];
      qv.x -= lw[4*g+0]; qv.y -= lw[4*g+1]; qv.z -= lw[4*g+2]; qv.w -= lw[4*g+3];
      *(float4*)&qwrow[j0 + 4 * g] = qv;
      float4 ov = {o0[4*g+0], o0[4*g+1], o0[4*g+2], o0[4*g+3]};
      *(float4*)&O0buf[(size_t)ch * 4096 + t * 64 + j0 + 4 * g] = ov;
    }
  }
  // phase 3: P/Z (reads Ksh/Wksh/U0sh only - untouched since staging; no barrier)
  {
    int d0 = seg * 16;
    float accP[16], accZ[16];
    #pragma unroll
    for (int r = 0; r < 16; r++) { accP[r] = 0.f; accZ[r] = 0.f; }
    for (int s = 0; s < 64; s++) {
      int sh = s >> 4;
      float kt = Ksh[s][(((t >> 2) ^ sh) << 2) + (t & 3)];   // K[s][t] via swizzle
      float u  = U0sh[s][t];
      #pragma unroll
      for (int g = 0; g < 4; g++) {
        float4 w4 = *(float4*)&Wksh[s][d0 + 4 * g];
        float4 k4 = *(float4*)&Ksh[s][(((seg * 4 + g) ^ sh) << 2)];  // K[s][d0+4g..]
        accP[4*g+0] += kt * w4.x; accP[4*g+1] += kt * w4.y; accP[4*g+2] += kt * w4.z; accP[4*g+3] += kt * w4.w;
        accZ[4*g+0] += u * k4.x;  accZ[4*g+1] += u * k4.y;  accZ[4*g+2] += u * k4.z;  accZ[4*g+3] += u * k4.w;
      }
    }
    float* zrow = kn + ((size_t)(b * T_ + c * 64 + t)) * D_ + h * 64;
    #pragma unroll
    for (int g = 0; g < 4; g++) {
      float4 pv;
      pv.x = ((d0 + 4*g + 0) == t ? 1.f : 0.f) - accP[4*g+0];
      pv.y = ((d0 + 4*g + 1) == t ? 1.f : 0.f) - accP[4*g+1];
      pv.z = ((d0 + 4*g + 2) == t ? 1.f : 0.f) - accP[4*g+2];
      pv.w = ((d0 + 4*g + 3) == t ? 1.f : 0.f) - accP[4*g+3];
      // slot-major: slot f = seg*4+g, row d = t
      *(float4*)&Pbuf[(size_t)ch * 4096 + (size_t)(seg * 4 + g) * 256 + (size_t)t * 4] = pv;
      float4 zv = {accZ[4*g+0], accZ[4*g+1], accZ[4*g+2], accZ[4*g+3]};
      *(float4*)&zrow[d0 + 4 * g] = zv;
    }
  }
}

// ---------- state scan: S_{c+1} = P_c S_c + Z_c; Sbuf transposed [ch][j][d] ----------
__global__ __launch_bounds__(256) void state_kernel(
    const float* __restrict__ kn /*Zt*/, const float* __restrict__ Pbuf /*slot-major*/,
    float* __restrict__ Sbuf) {
  __shared__ __align__(16) float Pl[2][4096];
  int bid = blockIdx.x;
  int bh = bid & 31, js = bid >> 5;
  int h = bh & 15, b = bh >> 4;
  int tid = threadIdx.x;
  int wv = tid >> 6, lane = tid & 63;   // lane = d
  int j0 = js * 4 + wv;                 // this wave's column
  float s0 = 0.f;
  const size_t bhNC = (size_t)bh * NC_;
  const float* Pg0 = Pbuf + bhNC * 4096;
  #pragma unroll
  for (int g = 0; g < 4; g++)
    __builtin_amdgcn_global_load_lds(
        (const __attribute__((address_space(1))) void*)(Pg0 + (g * 256 + tid) * 4),
        (__attribute__((address_space(3))) void*)&Pl[0][(g * 256 + tid) * 4], 16, 0, 0);
  float zn = kn[((size_t)(b * T_ + j0)) * D_ + h * 64 + lane];
  int cur = 0;
  #pragma unroll 1
  for (int c = 0; c < NC_; c++) {
    __syncthreads();            // implies vmcnt(0) drain: buf[cur] ready for all waves
    float z = zn;
    size_t ch = bhNC + c;
    if (c + 1 < NC_) {
      const float* Pg = Pbuf + (ch + 1) * 4096;
      #pragma unroll
      for (int g = 0; g < 4; g++)
        __builtin_amdgcn_global_load_lds(
            (const __attribute__((address_space(1))) void*)(Pg + (g * 256 + tid) * 4),
            (__attribute__((address_space(3))) void*)&Pl[cur ^ 1][(g * 256 + tid) * 4], 16, 0, 0);
      zn = kn[((size_t)(b * T_ + (c + 1) * 64 + j0)) * D_ + h * 64 + lane];
    }
    Sbuf[ch * 4096 + (size_t)j0 * 64 + lane] = s0;
    float acc = z;
    #pragma unroll
    for (int f = 0; f < 16; f++) {
      floatx4 pv = *(floatx4*)&Pl[cur][f * 256 + lane * 4];
      acc += pv.x * rdlane(s0, f * 4 + 0);
      acc += pv.y * rdlane(s0, f * 4 + 1);
      acc += pv.z * rdlane(s0, f * 4 + 2);
      acc += pv.w * rdlane(s0, f * 4 + 3);
    }
    s0 = acc;
    cur ^= 1;
  }
}

// ---------- O = O0 + Qeff*S_c (S transposed layout), fused RMSNorm + bf16 cast ----------
__global__ __launch_bounds__(256) void ophase_kernel(
    const float* __restrict__ qn /*Qeff*/, const float* __restrict__ Sbuf,
    const float* __restrict__ O0buf, const float* __restrict__ rms_g,
    ushort* __restrict__ ob) {
  __shared__ float Ssht[64][68];
  __shared__ float QshT[64][65];
  __shared__ float part[64][4];
  int ch = blockIdx.x;
  int b = ch >> 9, h = (ch >> 5) & 15, c = ch & 31;
  int tid = threadIdx.x;
  int t = tid & 63, jg = tid >> 6;
  #pragma unroll
  for (int g = 0; g < 4; g++) {
    int idx = tid + g * 256;
    *(float4*)&Ssht[idx >> 4][(idx & 15) * 4] =
        *(const float4*)&Sbuf[(size_t)ch * 4096 + (size_t)idx * 4];
  }
  #pragma unroll
  for (int g = 0; g < 4; g++) {
    int idx = tid + g * 256;
    int row = idx >> 4, c4 = idx & 15;
    float4 qv = *(const float4*)&qn[((size_t)(b * T_ + c * 64 + row)) * D_ + h * 64 + c4 * 4];
    QshT[c4 * 4 + 0][row] = qv.x;
    QshT[c4 * 4 + 1][row] = qv.y;
    QshT[c4 * 4 + 2][row] = qv.z;
    QshT[c4 * 4 + 3][row] = qv.w;
  }
  float o[16];
  #pragma unroll
  for (int g = 0; g < 4; g++) {
    float4 o4 = *(const float4*)&O0buf[(size_t)ch * 4096 + t * 64 + jg * 16 + g * 4];
    o[4*g+0] = o4.x; o[4*g+1] = o4.y; o[4*g+2] = o4.z; o[4*g+3] = o4.w;
  }
  __syncthreads();
  for (int d4 = 0; d4 < 16; d4++) {
    float q0 = QshT[d4 * 4 + 0][t];
    float q1 = QshT[d4 * 4 + 1][t];
    float q2 = QshT[d4 * 4 + 2][t];
    float q3 = QshT[d4 * 4 + 3][t];
    #pragma unroll
    for (int r = 0; r < 16; r++) {
      float4 s4 = *(float4*)&Ssht[jg * 16 + r][d4 * 4];
      o[r] += q0 * s4.x + q1 * s4.y + q2 * s4.z + q3 * s4.w;
    }
  }
  float ss = 0.f;
  #pragma unroll
  for (int r = 0; r < 16; r++) ss += o[r] * o[r];
  part[t][jg] = ss;
  __syncthreads();
  float tot = part[t][0] + part[t][1] + part[t][2] + part[t][3];
  float sc = rsqrtf(tot * (1.f / 64.f) + 1e-6f);
  ushort* orow = &ob[((size_t)(b * T_ + c * 64 + t)) * D_ + h * 64];
  #pragma unroll
  for (int g = 0; g < 4; g++) {
    float4 g4 = *(const float4*)&rms_g[jg * 16 + g * 4];
    ushort4 r4;
    r4.x = f2bf(o[4*g+0] * sc * g4.x); r4.y = f2bf(o[4*g+1] * sc * g4.y);
    r4.z = f2bf(o[4*g+2] * sc * g4.z); r4.w = f2bf(o[4*g+3] * sc * g4.w);
    *(ushort4*)&orow[jg * 16 + g * 4] = r4;
  }
}

extern "C" void kernel_launch(void* const* d_in, const int* in_sizes, int n_in,
                              void* d_out, int out_size, void* d_ws, size_t ws_size,
                              hipStream_t stream) {
  const float* x  = (const float*)d_in[0];
  const float* Wq = (const float*)d_in[1];
  const float* Wk = (const float*)d_in[2];
  const float* Wv = (const float*)d_in[3];
  const float* Wb = (const float*)d_in[4];
  const float* cq = (const float*)d_in[5];
  const float* ck = (const float*)d_in[6];
  const float* cv = (const float*)d_in[7];
  const float* rg = (const float*)d_in[8];
  const float* Wo = (const float*)d_in[9];
  float* out = (float*)d_out;
  char* ws = (char*)d_ws;
  const size_t MiB = 1ull << 20;
  ushort* xb   = (ushort*)(ws + 0);         // dead after QKV gemm
  ushort* Wqt  = (ushort*)(ws + 8 * MiB);   // Wqt/Wkt/Wvt contiguous = [3072][1024] bf16
  ushort* Wkt  = (ushort*)(ws + 10 * MiB);
  ushort* Wvt  = (ushort*)(ws + 12 * MiB);
  ushort* Wot  = (ushort*)(ws + 14 * MiB);  // live to end
  float* qkv   = (float*)(ws + 16 * MiB);   // [4096][3072] fp32, dead after conv
  float* qn    = (float*)(ws + 64 * MiB);   // then Qeff in-place
  float* kn    = (float*)(ws + 80 * MiB);   // then Zt in-place
  float* vn    = (float*)(ws + 96 * MiB);   // dead after prep1
  float* beta  = (float*)(ws + 112 * MiB);  // 256 KiB
  float* WbT   = (float*)(ws + 112 * MiB + 256 * 1024);  // 64 KiB
  float* Wkbuf = (float*)(ws + 16 * MiB);   // over qkv (dead after conv)
  float* U0buf = (float*)(ws + 32 * MiB);
  float* Pbuf  = (float*)(ws + 48 * MiB);   // P (prep2abc out, state in)
  float* O0buf = (float*)(ws + 96 * MiB);   // over vn (after prep1)
  float* Sbuf  = (float*)(ws + 16 * MiB);   // over Wkbuf (dead after prep2abc)
  ushort* ob   = (ushort*)(ws + 0);         // over xb (after QKV gemm)

  hipLaunchKernelGGL(cast_kernel, dim3(M_ * D_ / 4 / 256), dim3(256), 0, stream,
                     x, xb, M_ * D_ / 4);
  dim3 tb(32, 8);
  hipLaunchKernelGGL(transpose_cast4_kernel, dim3(32, 32, 4), tb, 0, stream,
                     Wq, Wk, Wv, Wo, Wqt, Wkt, Wvt, Wot);
  hipLaunchKernelGGL(transpose_wb_kernel, dim3(64), dim3(256), 0, stream, Wb, WbT);

  hipLaunchKernelGGL(gemm128_kernel, dim3(M_ / 128, QKVN_ / 128), dim3(256), 0, stream,
                     xb, Wqt, qkv, M_, QKVN_, D_);

  hipLaunchKernelGGL(beta_kernel, dim3(M_ / 16), dim3(256), 0, stream, x, WbT, beta);
  hipLaunchKernelGGL(conv_kernel, dim3(M_), dim3(256), 0, stream,
                     qkv, cq, ck, cv, qn, kn, vn);

  hipLaunchKernelGGL(prep1_kernel, dim3(NCH_), dim3(256), 0, stream,
                     kn, vn, beta, Wkbuf, U0buf);
  hipLaunchKernelGGL(prep2abc_kernel, dim3(NCH_), dim3(256), 0, stream,
                     qn, kn, Wkbuf, U0buf, O0buf, Pbuf);
  hipLaunchKernelGGL(state_kernel, dim3(512), dim3(256), 0, stream,
                     kn, Pbuf, Sbuf);
  hipLaunchKernelGGL(ophase_kernel, dim3(NCH_), dim3(256), 0, stream,
                     qn, Sbuf, O0buf, rg, ob);
  hipLaunchKernelGGL(gemm128_kernel, dim3(M_ / 128, D_ / 128), dim3(256), 0, stream,
                     ob, Wot, out, M_, D_, D_);
}

// Round 14
// 342.204 us; speedup vs baseline: 1.1090x; 1.0092x over previous
//
#include <hip/hip_runtime.h>
#include <hip/hip_bf16.h>
#include <math.h>

#define B_ 2
#define T_ 2048
#define D_ 1024
#define H_ 16
#define DH_ 64
#define M_ (B_*T_)   // 4096 rows
#define NC_ 32       // chunks per sequence (T/64)
#define CS_ 64       // chunk size
#define NCH_ (B_*H_*NC_)  // 1024 chunk-heads
#define QKVN_ 3072   // fused QKV gemm N

typedef __attribute__((ext_vector_type(4))) float floatx4;
typedef __attribute__((ext_vector_type(8))) short short8;

__device__ __forceinline__ ushort f2bf(float f) {
  union { float f; unsigned u; } c; c.f = f;
  unsigned r = (c.u + 0x7FFFu + ((c.u >> 16) & 1u)) >> 16;  // RNE
  return (ushort)r;
}
__device__ __forceinline__ float siluf(float u) {
  return u / (1.f + __expf(-u));
}
__device__ __forceinline__ float f4get(const float4& v, int j) {
  return j == 0 ? v.x : j == 1 ? v.y : j == 2 ? v.z : v.w;
}
__device__ __forceinline__ float rdlane(float v, int l) {
  return __int_as_float(__builtin_amdgcn_readlane(__float_as_int(v), l));
}
// swizzled chunk index for K tiles: chunk c (0..15) of row r stored at c ^ (r>>4)
__device__ __forceinline__ int ksw(int r, int c) { return ((c ^ (r >> 4)) << 2); }

// ---------- cast f32 -> bf16, n4 = n/4 ----------
__global__ void cast_kernel(const float* __restrict__ in, ushort* __restrict__ out, int n4) {
  int i = blockIdx.x * blockDim.x + threadIdx.x;
  if (i >= n4) return;
  float4 v = ((const float4*)in)[i];
  ushort4 o;
  o.x = f2bf(v.x); o.y = f2bf(v.y); o.z = f2bf(v.z); o.w = f2bf(v.w);
  ((ushort4*)out)[i] = o;
}

// ---------- transpose + cast x4 weights in one launch: W[1024][1024] f32 -> Wt bf16 ----------
__global__ void transpose_cast4_kernel(
    const float* __restrict__ W0, const float* __restrict__ W1,
    const float* __restrict__ W2, const float* __restrict__ W3,
    ushort* __restrict__ T0, ushort* __restrict__ T1,
    ushort* __restrict__ T2, ushort* __restrict__ T3) {
  __shared__ float tile[32][33];
  int z = blockIdx.z;
  const float* W = z == 0 ? W0 : z == 1 ? W1 : z == 2 ? W2 : W3;
  ushort* Wt = z == 0 ? T0 : z == 1 ? T1 : z == 2 ? T2 : T3;
  int tx = threadIdx.x, ty = threadIdx.y;
  int n0 = blockIdx.x * 32, k0 = blockIdx.y * 32;
  #pragma unroll
  for (int i = 0; i < 32; i += 8)
    tile[ty + i][tx] = W[(size_t)(k0 + ty + i) * D_ + n0 + tx];
  __syncthreads();
  #pragma unroll
  for (int i = 0; i < 32; i += 8)
    Wt[(size_t)(n0 + ty + i) * D_ + k0 + tx] = f2bf(tile[tx][ty + i]);
}

// ---------- transpose Wb[1024][16] -> WbT[16][1024] (fp32) ----------
__global__ void transpose_wb_kernel(const float* __restrict__ Wb, float* __restrict__ WbT) {
  int bk = blockIdx.x;
  int tid = threadIdx.x;
  int kl = tid >> 4, h = tid & 15;
  int k = bk * 16 + kl;
  WbT[(size_t)h * D_ + k] = Wb[(size_t)k * H_ + h];
}

// ---------- bf16 MFMA GEMM, 2-phase counted-vmcnt pipeline + XCD supertile swizzle ----------
__global__ __launch_bounds__(256) void gemm128_kernel(
    const ushort* __restrict__ A, const ushort* __restrict__ Bt,
    float* __restrict__ C, int M, int N, int K) {
  __shared__ ushort lA[2][128 * 32];
  __shared__ ushort lB[2][128 * 32];
  int tid = threadIdx.x;
  int wave = tid >> 6, lane = tid & 63;
  int wm = wave >> 1, wn = wave & 1;
  int m16 = lane & 15, q4 = lane >> 4;
  // XCD-aware bijective swizzle with 8x8 supertiles
  int nbm = gridDim.x, nbn = gridDim.y;
  int lin = blockIdx.y * nbm + blockIdx.x;
  int cpx = (nbm * nbn) >> 3;
  int swz = (lin & 7) * cpx + (lin >> 3);
  int stn = nbn >> 3;
  int st = swz >> 6, in_ = swz & 63;
  int stm = st / stn, soff = st - stm * stn;
  int bm = stm * 8 + (in_ & 7);
  int bn = soff * 8 + (in_ >> 3);
  floatx4 acc[4][4] = {};
  int srow = tid >> 2;
  int sk8 = tid & 3;
  const ushort* Ag = A + (size_t)(bm * 128 + srow) * K + sk8 * 8;
  const ushort* Bg = Bt + (size_t)(bn * 128 + srow) * K + sk8 * 8;
  int nks = K >> 5;

#define GSTAGE(bufi, kk0)                                                       \
  {                                                                             \
    __builtin_amdgcn_global_load_lds(                                           \
        (const __attribute__((address_space(1))) void*)(Ag + (kk0)),            \
        (__attribute__((address_space(3))) void*)&lA[bufi][tid * 8], 16, 0, 0); \
    __builtin_amdgcn_global_load_lds(                                           \
        (const __attribute__((address_space(1))) void*)(Ag + (size_t)64 * K + (kk0)), \
        (__attribute__((address_space(3))) void*)&lA[bufi][tid * 8 + 2048], 16, 0, 0); \
    __builtin_amdgcn_global_load_lds(                                           \
        (const __attribute__((address_space(1))) void*)(Bg + (kk0)),            \
        (__attribute__((address_space(3))) void*)&lB[bufi][tid * 8], 16, 0, 0); \
    __builtin_amdgcn_global_load_lds(                                           \
        (const __attribute__((address_space(1))) void*)(Bg + (size_t)64 * K + (kk0)), \
        (__attribute__((address_space(3))) void*)&lB[bufi][tid * 8 + 2048], 16, 0, 0); \
  }

  GSTAGE(0, 0);
  int cur = 0;
  #pragma unroll 1
  for (int ks = 0; ks < nks; ++ks) {
    if (ks + 1 < nks) {
      GSTAGE(cur ^ 1, (ks + 1) * 32);
      asm volatile("s_waitcnt vmcnt(4)" ::: "memory");
    } else {
      asm volatile("s_waitcnt vmcnt(0)" ::: "memory");
    }
    __builtin_amdgcn_s_barrier();       // buf[cur] staged & visible
    __builtin_amdgcn_sched_barrier(0);
    short8 af[4], bf[4];
    #pragma unroll
    for (int i = 0; i < 4; i++) {
      af[i] = *(short8*)&lA[cur][(wm * 64 + i * 16 + m16) * 32 + q4 * 8];
      bf[i] = *(short8*)&lB[cur][(wn * 64 + i * 16 + m16) * 32 + q4 * 8];
    }
    #pragma unroll
    for (int mi = 0; mi < 4; mi++)
      #pragma unroll
      for (int nj = 0; nj < 4; nj++)
        acc[mi][nj] = __builtin_amdgcn_mfma_f32_16x16x32_bf16(af[mi], bf[nj], acc[mi][nj], 0, 0, 0);
    __builtin_amdgcn_s_barrier();       // all waves done reading buf[cur]
    cur ^= 1;
  }
#undef GSTAGE
  float* Cb = C + (size_t)(bm * 128) * N + bn * 128;
  #pragma unroll
  for (int mi = 0; mi < 4; mi++) {
    #pragma unroll
    for (int nj = 0; nj < 4; nj++) {
      #pragma unroll
      for (int i = 0; i < 4; i++) {
        int row = wm * 64 + mi * 16 + q4 * 4 + i;
        int col = wn * 64 + nj * 16 + m16;
        Cb[(size_t)row * N + col] = acc[mi][nj][i];
      }
    }
  }
}

// ---------- beta = sigmoid(x @ Wb): blocked GEMV, 16 rows/block ----------
__global__ __launch_bounds__(256) void beta_kernel(const float* __restrict__ x,
                                                   const float* __restrict__ WbT,
                                                   float* __restrict__ beta) {
  __shared__ __align__(16) float4 wsh[16][256];   // 64 KB
  int tid = threadIdx.x;
  const float4* Wb4 = (const float4*)WbT;
  #pragma unroll
  for (int i = 0; i < 16; i++) {
    int idx = i * 256 + tid;
    int h = idx >> 8, c = idx & 255;
    wsh[h][c ^ (h & 7)] = Wb4[h * 256 + c];
  }
  __syncthreads();
  int r = tid >> 4, h = tid & 15;
  int hs = h & 7;
  int row = blockIdx.x * 16 + r;
  const float4* xr = (const float4*)(x + (size_t)row * D_);
  float acc0 = 0.f, acc1 = 0.f, acc2 = 0.f, acc3 = 0.f;
  #pragma unroll 8
  for (int c = 0; c < 256; c += 4) {
    float4 x0 = xr[c + 0], x1 = xr[c + 1], x2 = xr[c + 2], x3 = xr[c + 3];
    float4 w0 = wsh[h][(c + 0) ^ hs];
    float4 w1 = wsh[h][(c + 1) ^ hs];
    float4 w2 = wsh[h][(c + 2) ^ hs];
    float4 w3 = wsh[h][(c + 3) ^ hs];
    acc0 += x0.x * w0.x + x0.y * w0.y + x0.z * w0.z + x0.w * w0.w;
    acc1 += x1.x * w1.x + x1.y * w1.y + x1.z * w1.z + x1.w * w1.w;
    acc2 += x2.x * w2.x + x2.y * w2.y + x2.z * w2.z + x2.w * w2.w;
    acc3 += x3.x * w3.x + x3.y * w3.y + x3.z * w3.z + x3.w * w3.w;
  }
  float s = (acc0 + acc1) + (acc2 + acc3);
  beta[(size_t)row * H_ + h] = 1.f / (1.f + __expf(-s));
}

// ---------- causal depthwise conv(K=4) + silu, l2norm for q,k ----------
__global__ __launch_bounds__(256) void conv_kernel(
    const float* __restrict__ qkv,
    const float* __restrict__ cq, const float* __restrict__ ck, const float* __restrict__ cv,
    float* __restrict__ qo, float* __restrict__ ko, float* __restrict__ vo) {
  int row = blockIdx.x;
  int t = row & (T_ - 1);
  int tid = threadIdx.x;
  int c0 = tid * 4;
  float4 zf = {0.f, 0.f, 0.f, 0.f};
  float4 xq[4], xk[4], xv[4];
  #pragma unroll
  for (int i = 0; i < 4; i++) {
    int tt = t - 3 + i;
    if (tt >= 0) {
      const float* rp = qkv + (size_t)(row - 3 + i) * QKVN_;
      xq[i] = *(const float4*)(rp + c0);
      xk[i] = *(const float4*)(rp + 1024 + c0);
      xv[i] = *(const float4*)(rp + 2048 + c0);
    } else { xq[i] = zf; xk[i] = zf; xv[i] = zf; }
  }
  float yq[4], yk[4], yv[4];
  float pq = 0.f, pk = 0.f;
  #pragma unroll
  for (int j = 0; j < 4; j++) {
    float4 wq = ((const float4*)cq)[c0 + j];
    float4 wk = ((const float4*)ck)[c0 + j];
    float4 wv = ((const float4*)cv)[c0 + j];
    float sq = 0.f, sk = 0.f, sv = 0.f;
    #pragma unroll
    for (int i = 0; i < 4; i++) {
      sq += f4get(wq, i) * f4get(xq[i], j);
      sk += f4get(wk, i) * f4get(xk[i], j);
      sv += f4get(wv, i) * f4get(xv[i], j);
    }
    yq[j] = siluf(sq); yk[j] = siluf(sk); yv[j] = siluf(sv);
    pq += yq[j] * yq[j]; pk += yk[j] * yk[j];
  }
  #pragma unroll
  for (int off = 1; off < 16; off <<= 1) {
    pq += __shfl_xor(pq, off, 16);
    pk += __shfl_xor(pk, off, 16);
  }
  float rq = rsqrtf(pq + 1e-6f), rk = rsqrtf(pk + 1e-6f);
  float4 oq = {yq[0]*rq, yq[1]*rq, yq[2]*rq, yq[3]*rq};
  float4 okk = {yk[0]*rk, yk[1]*rk, yk[2]*rk, yk[3]*rk};
  float4 ov = {yv[0], yv[1], yv[2], yv[3]};
  *(float4*)(qo + (size_t)row * D_ + c0) = oq;
  *(float4*)(ko + (size_t)row * D_ + c0) = okk;
  *(float4*)(vo + (size_t)row * D_ + c0) = ov;
}

// ================= chunked delta rule =================
// prep1: A = strict_tril(diag(b)KK^T); solve (I+A)Wk = diag(b)K and (I+A)U0 = diag(b)V
// A-phase via split-bf16 MFMA (hi/lo split in staging loop; bank-staggered LDS,
// XOR-16 involution on write and read). Solve phases R3-verified.
__global__ __launch_bounds__(256) void prep1_kernel(
    const float* __restrict__ kn, const float* __restrict__ vn,
    const float* __restrict__ beta,
    float* __restrict__ Wkbuf, float* __restrict__ U0buf) {
  __shared__ __align__(16) float Ash[64 * 68];   // A[t][s] row-major, stride 68
  __shared__ float bsh[64];
  __shared__ __align__(16) float uni[5312];
  ushort* KH = (ushort*)uni;                                // 64 rows x 160B = 10240B
  ushort* KL = (ushort*)uni + 5120;                         // next 10240B
  float (*Tsh)[16][20] = (float (*)[16][20])uni;            // [4][16][20] = 1280
  float (*Msh)[16][20] = (float (*)[16][20])(uni + 1280);   // [6][16][20] = 1920
  float (*Xsh)[132] = (float (*)[132])(uni + 3200);         // [16][132]  = 2112

  int ch = blockIdx.x;
  int b = ch >> 9, h = (ch >> 5) & 15, c = ch & 31;
  int tid = threadIdx.x;
  int t = tid >> 2, seg = tid & 3;
  int wave = tid >> 6, lane = tid & 63;
  int r = lane >> 2, q = lane & 3;   // r == t&15, q == seg
  int m16 = lane & 15, oct = lane >> 4;
  const float* kg = kn + ((size_t)(b * T_ + c * 64)) * D_ + h * 64;
  {
    #pragma unroll
    for (int p = 0; p < 2; p++) {
      int idx = p * 256 + tid;          // 16B dest unit
      int row = idx >> 3, cb = (idx & 7) * 16;
      int scb = cb ^ ((row & 7) << 4);  // source byte col (bf16 units)
      const float* src = kg + (size_t)row * D_ + (scb >> 1);
      float4 va = *(const float4*)src;
      float4 vb = *(const float4*)(src + 4);
      float v[8] = {va.x, va.y, va.z, va.w, vb.x, vb.y, vb.z, vb.w};
      short8 hi8, lo8;
      #pragma unroll
      for (int j = 0; j < 8; j++) {
        unsigned u = __float_as_uint(v[j]);
        hi8[j] = (short)(u >> 16);                      // truncated bf16 hi
        lo8[j] = (short)f2bf(v[j] - __uint_as_float(u & 0xFFFF0000u));
      }
      *(short8*)((char*)KH + row * 160 + cb) = hi8;
      *(short8*)((char*)KL + row * 160 + cb) = lo8;
    }
  }
  if (tid < 64) bsh[tid] = beta[((size_t)(b * T_ + c * 64 + tid)) * H_ + h];
  __syncthreads();
  // A[t][s] = (t>s) ? b_t * (k_t . k_s) : 0 — split-bf16 MFMA; wave w owns row-tile w
  {
    floatx4 acc[4] = {};
    #pragma unroll
    for (int ks = 0; ks < 2; ks++) {
      int ob = (ks * 64 + oct * 16) ^ ((m16 & 7) << 4);
      short8 fah = *(short8*)((char*)KH + (wave * 16 + m16) * 160 + ob);
      short8 fal = *(short8*)((char*)KL + (wave * 16 + m16) * 160 + ob);
      #pragma unroll
      for (int si = 0; si < 4; si++) {
        short8 fbh = *(short8*)((char*)KH + (si * 16 + m16) * 160 + ob);
        short8 fbl = *(short8*)((char*)KL + (si * 16 + m16) * 160 + ob);
        acc[si] = __builtin_amdgcn_mfma_f32_16x16x32_bf16(fah, fbh, acc[si], 0, 0, 0);
        acc[si] = __builtin_amdgcn_mfma_f32_16x16x32_bf16(fah, fbl, acc[si], 0, 0, 0);
        acc[si] = __builtin_amdgcn_mfma_f32_16x16x32_bf16(fal, fbh, acc[si], 0, 0, 0);
      }
    }
    #pragma unroll
    for (int si = 0; si < 4; si++) {
      #pragma unroll
      for (int rr = 0; rr < 4; rr++) {
        int row = wave * 16 + oct * 4 + rr;
        int col = si * 16 + m16;
        float bt = bsh[row];
        Ash[row * 68 + col] = (row > col) ? bt * acc[si][rr] : 0.f;
      }
    }
  }
  // RHS (residual Y) in registers: row t, 16 K-cols + 16 V-cols (fp32 from global)
  float xk[16], xv[16];
  {
    float bt = bsh[t];
    const float* krow = kn + ((size_t)(b * T_ + c * 64 + t)) * D_ + h * 64;
    const float* vrow = vn + ((size_t)(b * T_ + c * 64 + t)) * D_ + h * 64;
    #pragma unroll
    for (int g = 0; g < 4; g++) {
      float4 kv = *(const float4*)&krow[seg * 16 + 4 * g];
      float4 vv = *(const float4*)&vrow[seg * 16 + 4 * g];
      xk[4*g+0] = bt * kv.x; xk[4*g+1] = bt * kv.y; xk[4*g+2] = bt * kv.z; xk[4*g+3] = bt * kv.w;
      xv[4*g+0] = bt * vv.x; xv[4*g+1] = bt * vv.y; xv[4*g+2] = bt * vv.z; xv[4*g+3] = bt * vv.w;
    }
  }
  __syncthreads();   // Ash ready; KH/KL dead -> Tsh/Msh/Xsh region live
  // Phase A: wave-parallel 16x16 diagonal-block inverse via fwd substitution on I
  {
    float a[16];
    #pragma unroll
    for (int i = 0; i < 16; i++) a[i] = Ash[(wave * 16 + r) * 68 + wave * 16 + i];
    float4 w4 = {0.f, 0.f, 0.f, 0.f};
    if ((r >> 2) == q) ((float*)&w4)[r & 3] = 1.f;
    #pragma unroll
    for (int i = 0; i < 15; i++) {
      int src = i * 4 + q;
      float4 wi;
      wi.x = __shfl(w4.x, src, 64);
      wi.y = __shfl(w4.y, src, 64);
      wi.z = __shfl(w4.z, src, 64);
      wi.w = __shfl(w4.w, src, 64);
      if (r > i) {
        w4.x -= a[i] * wi.x; w4.y -= a[i] * wi.y;
        w4.z -= a[i] * wi.z; w4.w -= a[i] * wi.w;
      }
    }
    *(float4*)&Tsh[wave][r][q * 4] = w4;
  }
  __syncthreads();   // Tsh visible to all waves
  // Phase B: M_wk = A_wk * T_kk (wave-local write, wave-local read)
  for (int k = 0; k < wave; k++) {
    float4 m4 = {0.f, 0.f, 0.f, 0.f};
    #pragma unroll
    for (int i = 0; i < 16; i++) {
      float aik = Ash[(wave * 16 + r) * 68 + k * 16 + i];
      float4 tk = *(float4*)&Tsh[k][i][q * 4];
      m4.x += aik * tk.x; m4.y += aik * tk.y;
      m4.z += aik * tk.z; m4.w += aik * tk.w;
    }
    int mi = wave * (wave - 1) / 2 + k;
    *(float4*)&Msh[mi][r][q * 4] = m4;
  }
  // Block substitution k-loop
  float* wkout = &Wkbuf[(size_t)ch * 4096 + t * 64];
  float* u0out = &U0buf[(size_t)ch * 4096 + t * 64];
  for (int k = 0; k < 4; k++) {
    if (wave == k) {   // publish residual Y_k
      #pragma unroll
      for (int g = 0; g < 4; g++) {
        float4 k4 = {xk[4*g+0], xk[4*g+1], xk[4*g+2], xk[4*g+3]};
        float4 v4 = {xv[4*g+0], xv[4*g+1], xv[4*g+2], xv[4*g+3]};
        *(float4*)&Xsh[r][seg * 16 + 4 * g] = k4;
        *(float4*)&Xsh[r][64 + seg * 16 + 4 * g] = v4;
      }
    }
    __syncthreads();
    if (wave == k) {
      // X_k = T_kk * Y_k -> final output, straight to global
      float nk[16], nv[16];
      #pragma unroll
      for (int i2 = 0; i2 < 16; i2++) { nk[i2] = 0.f; nv[i2] = 0.f; }
      #pragma unroll
      for (int i = 0; i < 16; i++) {
        float tc = Tsh[k][r][i];
        #pragma unroll
        for (int g = 0; g < 4; g++) {
          float4 yk = *(float4*)&Xsh[i][seg * 16 + 4 * g];
          float4 yv = *(float4*)&Xsh[i][64 + seg * 16 + 4 * g];
          nk[4*g+0] += tc * yk.x; nk[4*g+1] += tc * yk.y;
          nk[4*g+2] += tc * yk.z; nk[4*g+3] += tc * yk.w;
          nv[4*g+0] += tc * yv.x; nv[4*g+1] += tc * yv.y;
          nv[4*g+2] += tc * yv.z; nv[4*g+3] += tc * yv.w;
        }
      }
      #pragma unroll
      for (int g = 0; g < 4; g++) {
        float4 k4 = {nk[4*g+0], nk[4*g+1], nk[4*g+2], nk[4*g+3]};
        float4 v4 = {nv[4*g+0], nv[4*g+1], nv[4*g+2], nv[4*g+3]};
        *(float4*)&wkout[seg * 16 + 4 * g] = k4;
        *(float4*)&u0out[seg * 16 + 4 * g] = v4;
      }
    } else if (wave > k) {
      // Y_i -= M_ik * Y_k   (== A_ik * X_k)
      int mi = wave * (wave - 1) / 2 + k;
      #pragma unroll
      for (int i = 0; i < 16; i++) {
        float mc = Msh[mi][r][i];
        #pragma unroll
        for (int g = 0; g < 4; g++) {
          float4 yk = *(float4*)&Xsh[i][seg * 16 + 4 * g];
          float4 yv = *(float4*)&Xsh[i][64 + seg * 16 + 4 * g];
          xk[4*g+0] -= mc * yk.x; xk[4*g+1] -= mc * yk.y;
          xk[4*g+2] -= mc * yk.z; xk[4*g+3] -= mc * yk.w;
          xv[4*g+0] -= mc * yv.x; xv[4*g+1] -= mc * yv.y;
          xv[4*g+2] -= mc * yv.z; xv[4*g+3] -= mc * yv.w;
        }
      }
    }
    __syncthreads();
  }
}

// prep2abc: fused prep2a+prep2b+prep2c, ALL phases 4x4-register-tiled.
//   phase 1: L = tril(Q K^T) -> overwrite dead Q buffer with L
//   phase 2: O0 = L U0 ; Qeff = Q - L Wk  (4x4 tile; s loops 0..63 — L's upper
//            triangle is stored zeros so extra terms add 0.0, bit-identical)
//   phase 3: P = I - K^T Wk (slot-major) ; Zt = U0^T K  (4x4 outer-product tile)
// Per-thread LDS reads ~900 -> ~575 float4. Accumulation order unchanged.
__global__ __launch_bounds__(256) void prep2abc_kernel(
    float* qn, float* kn,
    const float* __restrict__ Wkbuf, const float* __restrict__ U0buf,
    float* __restrict__ O0buf, float* __restrict__ Pbuf) {
  __shared__ float Ash[64][68];   // Q, then L
  __shared__ float Ksh[64][68];   // swizzled K (persistent)
  __shared__ float Wksh[64][68];  // persistent
  __shared__ float U0sh[64][68];  // persistent
  int ch = blockIdx.x;
  int b = ch >> 9, h = (ch >> 5) & 15, c = ch & 31;
  int tid = threadIdx.x;
  int t = tid >> 2, seg = tid & 3;
  int qt = tid >> 4, qs = tid & 15;
  const float* qrow = qn + ((size_t)(b * T_ + c * 64 + t)) * D_ + h * 64;
  const float* krow = kn + ((size_t)(b * T_ + c * 64 + t)) * D_ + h * 64;
  #pragma unroll
  for (int g = 0; g < 4; g++) {
    int o = t * 64 + seg * 16 + 4 * g;
    *(float4*)&Ash[t][seg * 16 + 4 * g] = *(const float4*)&qrow[seg * 16 + 4 * g];
    *(float4*)&Ksh[t][ksw(t, seg * 4 + g)] = *(const float4*)&krow[seg * 16 + 4 * g];
    *(float4*)&Wksh[t][seg * 16 + 4 * g] = *(const float4*)&Wkbuf[(size_t)ch * 4096 + o];
    *(float4*)&U0sh[t][seg * 16 + 4 * g] = *(const float4*)&U0buf[(size_t)ch * 4096 + o];
  }
  __syncthreads();
  // phase 1: L = tril(Q K^T), 4x4 register tile per thread (Q read from Ash)
  float accL[4][4];
  {
    int sws = qs >> 2;
    #pragma unroll
    for (int i = 0; i < 4; i++)
      #pragma unroll
      for (int j = 0; j < 4; j++) accL[i][j] = 0.f;
    for (int d4 = 0; d4 < 16; d4++) {
      float4 qv[4], ks[4];
      #pragma unroll
      for (int i = 0; i < 4; i++) qv[i] = *(float4*)&Ash[qt * 4 + i][d4 * 4];
      #pragma unroll
      for (int j = 0; j < 4; j++) ks[j] = *(float4*)&Ksh[qs * 4 + j][((d4 ^ sws) << 2)];
      #pragma unroll
      for (int i = 0; i < 4; i++)
        #pragma unroll
        for (int j = 0; j < 4; j++)
          accL[i][j] += qv[i].x * ks[j].x + qv[i].y * ks[j].y
                      + qv[i].z * ks[j].z + qv[i].w * ks[j].w;
    }
  }
  __syncthreads();   // all Q reads done; Ash may be overwritten with L
  #pragma unroll
  for (int i = 0; i < 4; i++) {
    int row = qt * 4 + i;
    float4 ov;
    ov.x = (qs * 4 + 0 <= row) ? accL[i][0] : 0.f;
    ov.y = (qs * 4 + 1 <= row) ? accL[i][1] : 0.f;
    ov.z = (qs * 4 + 2 <= row) ? accL[i][2] : 0.f;
    ov.w = (qs * 4 + 3 <= row) ? accL[i][3] : 0.f;
    *(float4*)&Ash[row][qs * 4] = ov;
  }
  __syncthreads();   // L visible
  // phase 2: O0 = L U0 ; Qeff = Q - L Wk, 4x4 tile (rows qt*4..+3, cols qs*4..+3)
  {
    float o0[4][4], lw[4][4];
    #pragma unroll
    for (int i = 0; i < 4; i++)
      #pragma unroll
      for (int j = 0; j < 4; j++) { o0[i][j] = 0.f; lw[i][j] = 0.f; }
    for (int s = 0; s < 64; s++) {
      float4 u = *(float4*)&U0sh[s][qs * 4];
      float4 w = *(float4*)&Wksh[s][qs * 4];
      #pragma unroll
      for (int i = 0; i < 4; i++) {
        float l = Ash[qt * 4 + i][s];
        o0[i][0] += l * u.x; o0[i][1] += l * u.y; o0[i][2] += l * u.z; o0[i][3] += l * u.w;
        lw[i][0] += l * w.x; lw[i][1] += l * w.y; lw[i][2] += l * w.z; lw[i][3] += l * w.w;
      }
    }
    #pragma unroll
    for (int i = 0; i < 4; i++) {
      int row = qt * 4 + i;
      float* qwrow = qn + ((size_t)(b * T_ + c * 64 + row)) * D_ + h * 64 + qs * 4;
      float4 qv = *(const float4*)qwrow;
      qv.x -= lw[i][0]; qv.y -= lw[i][1]; qv.z -= lw[i][2]; qv.w -= lw[i][3];
      *(float4*)qwrow = qv;
      float4 ov = {o0[i][0], o0[i][1], o0[i][2], o0[i][3]};
      *(float4*)&O0buf[(size_t)ch * 4096 + row * 64 + qs * 4] = ov;
    }
  }
  // phase 3: P/Z 4x4 outer-product tile (reads Ksh/Wksh/U0sh only; no barrier)
  {
    float accP[4][4], accZ[4][4];
    #pragma unroll
    for (int i = 0; i < 4; i++)
      #pragma unroll
      for (int j = 0; j < 4; j++) { accP[i][j] = 0.f; accZ[i][j] = 0.f; }
    for (int s = 0; s < 64; s++) {
      int sh = s >> 4;
      float4 w4  = *(float4*)&Wksh[s][qs * 4];
      float4 k4  = *(float4*)&Ksh[s][((qs ^ sh) << 2)];   // K[s][qs*4..+3]
      float4 kt4 = *(float4*)&Ksh[s][((qt ^ sh) << 2)];   // K[s][qt*4..+3]
      float4 u4  = *(float4*)&U0sh[s][qt * 4];
      #pragma unroll
      for (int i = 0; i < 4; i++) {
        float kt = f4get(kt4, i);
        float u  = f4get(u4, i);
        accP[i][0] += kt * w4.x; accP[i][1] += kt * w4.y;
        accP[i][2] += kt * w4.z; accP[i][3] += kt * w4.w;
        accZ[i][0] += u * k4.x;  accZ[i][1] += u * k4.y;
        accZ[i][2] += u * k4.z;  accZ[i][3] += u * k4.w;
      }
    }
    #pragma unroll
    for (int i = 0; i < 4; i++) {
      int row = qt * 4 + i;        // P row d / Z row j
      float4 pv;
      pv.x = ((qs * 4 + 0) == row ? 1.f : 0.f) - accP[i][0];
      pv.y = ((qs * 4 + 1) == row ? 1.f : 0.f) - accP[i][1];
      pv.z = ((qs * 4 + 2) == row ? 1.f : 0.f) - accP[i][2];
      pv.w = ((qs * 4 + 3) == row ? 1.f : 0.f) - accP[i][3];
      // slot-major: slot f = qs, row d = row
      *(float4*)&Pbuf[(size_t)ch * 4096 + (size_t)qs * 256 + (size_t)row * 4] = pv;
      float4 zv = {accZ[i][0], accZ[i][1], accZ[i][2], accZ[i][3]};
      *(float4*)&kn[((size_t)(b * T_ + c * 64 + row)) * D_ + h * 64 + qs * 4] = zv;
    }
  }
}

// ---------- state scan: S_{c+1} = P_c S_c + Z_c; Sbuf transposed [ch][j][d] ----------
__global__ __launch_bounds__(256) void state_kernel(
    const float* __restrict__ kn /*Zt*/, const float* __restrict__ Pbuf /*slot-major*/,
    float* __restrict__ Sbuf) {
  __shared__ __align__(16) float Pl[2][4096];
  int bid = blockIdx.x;
  int bh = bid & 31, js = bid >> 5;
  int h = bh & 15, b = bh >> 4;
  int tid = threadIdx.x;
  int wv = tid >> 6, lane = tid & 63;   // lane = d
  int j0 = js * 4 + wv;                 // this wave's column
  float s0 = 0.f;
  const size_t bhNC = (size_t)bh * NC_;
  const float* Pg0 = Pbuf + bhNC * 4096;
  #pragma unroll
  for (int g = 0; g < 4; g++)
    __builtin_amdgcn_global_load_lds(
        (const __attribute__((address_space(1))) void*)(Pg0 + (g * 256 + tid) * 4),
        (__attribute__((address_space(3))) void*)&Pl[0][(g * 256 + tid) * 4], 16, 0, 0);
  float zn = kn[((size_t)(b * T_ + j0)) * D_ + h * 64 + lane];
  int cur = 0;
  #pragma unroll 1
  for (int c = 0; c < NC_; c++) {
    __syncthreads();            // implies vmcnt(0) drain: buf[cur] ready for all waves
    float z = zn;
    size_t ch = bhNC + c;
    if (c + 1 < NC_) {
      const float* Pg = Pbuf + (ch + 1) * 4096;
      #pragma unroll
      for (int g = 0; g < 4; g++)
        __builtin_amdgcn_global_load_lds(
            (const __attribute__((address_space(1))) void*)(Pg + (g * 256 + tid) * 4),
            (__attribute__((address_space(3))) void*)&Pl[cur ^ 1][(g * 256 + tid) * 4], 16, 0, 0);
      zn = kn[((size_t)(b * T_ + (c + 1) * 64 + j0)) * D_ + h * 64 + lane];
    }
    Sbuf[ch * 4096 + (size_t)j0 * 64 + lane] = s0;
    float acc = z;
    #pragma unroll
    for (int f = 0; f < 16; f++) {
      floatx4 pv = *(floatx4*)&Pl[cur][f * 256 + lane * 4];
      acc += pv.x * rdlane(s0, f * 4 + 0);
      acc += pv.y * rdlane(s0, f * 4 + 1);
      acc += pv.z * rdlane(s0, f * 4 + 2);
      acc += pv.w * rdlane(s0, f * 4 + 3);
    }
    s0 = acc;
    cur ^= 1;
  }
}

// ---------- O = O0 + Qeff*S_c (S transposed layout), fused RMSNorm + bf16 cast ----------
__global__ __launch_bounds__(256) void ophase_kernel(
    const float* __restrict__ qn /*Qeff*/, const float* __restrict__ Sbuf,
    const float* __restrict__ O0buf, const float* __restrict__ rms_g,
    ushort* __restrict__ ob) {
  __shared__ float Ssht[64][68];
  __shared__ float QshT[64][65];
  __shared__ float part[64][4];
  int ch = blockIdx.x;
  int b = ch >> 9, h = (ch >> 5) & 15, c = ch & 31;
  int tid = threadIdx.x;
  int t = tid & 63, jg = tid >> 6;
  #pragma unroll
  for (int g = 0; g < 4; g++) {
    int idx = tid + g * 256;
    *(float4*)&Ssht[idx >> 4][(idx & 15) * 4] =
        *(const float4*)&Sbuf[(size_t)ch * 4096 + (size_t)idx * 4];
  }
  #pragma unroll
  for (int g = 0; g < 4; g++) {
    int idx = tid + g * 256;
    int row = idx >> 4, c4 = idx & 15;
    float4 qv = *(const float4*)&qn[((size_t)(b * T_ + c * 64 + row)) * D_ + h * 64 + c4 * 4];
    QshT[c4 * 4 + 0][row] = qv.x;
    QshT[c4 * 4 + 1][row] = qv.y;
    QshT[c4 * 4 + 2][row] = qv.z;
    QshT[c4 * 4 + 3][row] = qv.w;
  }
  float o[16];
  #pragma unroll
  for (int g = 0; g < 4; g++) {
    float4 o4 = *(const float4*)&O0buf[(size_t)ch * 4096 + t * 64 + jg * 16 + g * 4];
    o[4*g+0] = o4.x; o[4*g+1] = o4.y; o[4*g+2] = o4.z; o[4*g+3] = o4.w;
  }
  __syncthreads();
  for (int d4 = 0; d4 < 16; d4++) {
    float q0 = QshT[d4 * 4 + 0][t];
    float q1 = QshT[d4 * 4 + 1][t];
    float q2 = QshT[d4 * 4 + 2][t];
    float q3 = QshT[d4 * 4 + 3][t];
    #pragma unroll
    for (int r = 0; r < 16; r++) {
      float4 s4 = *(float4*)&Ssht[jg * 16 + r][d4 * 4];
      o[r] += q0 * s4.x + q1 * s4.y + q2 * s4.z + q3 * s4.w;
    }
  }
  float ss = 0.f;
  #pragma unroll
  for (int r = 0; r < 16; r++) ss += o[r] * o[r];
  part[t][jg] = ss;
  __syncthreads();
  float tot = part[t][0] + part[t][1] + part[t][2] + part[t][3];
  float sc = rsqrtf(tot * (1.f / 64.f) + 1e-6f);
  ushort* orow = &ob[((size_t)(b * T_ + c * 64 + t)) * D_ + h * 64];
  #pragma unroll
  for (int g = 0; g < 4; g++) {
    float4 g4 = *(const float4*)&rms_g[jg * 16 + g * 4];
    ushort4 r4;
    r4.x = f2bf(o[4*g+0] * sc * g4.x); r4.y = f2bf(o[4*g+1] * sc * g4.y);
    r4.z = f2bf(o[4*g+2] * sc * g4.z); r4.w = f2bf(o[4*g+3] * sc * g4.w);
    *(ushort4*)&orow[jg * 16 + g * 4] = r4;
  }
}

extern "C" void kernel_launch(void* const* d_in, const int* in_sizes, int n_in,
                              void* d_out, int out_size, void* d_ws, size_t ws_size,
                              hipStream_t stream) {
  const float* x  = (const float*)d_in[0];
  const float* Wq = (const float*)d_in[1];
  const float* Wk = (const float*)d_in[2];
  const float* Wv = (const float*)d_in[3];
  const float* Wb = (const float*)d_in[4];
  const float* cq = (const float*)d_in[5];
  const float* ck = (const float*)d_in[6];
  const float* cv = (const float*)d_in[7];
  const float* rg = (const float*)d_in[8];
  const float* Wo = (const float*)d_in[9];
  float* out = (float*)d_out;
  char* ws = (char*)d_ws;
  const size_t MiB = 1ull << 20;
  ushort* xb   = (ushort*)(ws + 0);         // dead after QKV gemm
  ushort* Wqt  = (ushort*)(ws + 8 * MiB);   // Wqt/Wkt/Wvt contiguous = [3072][1024] bf16
  ushort* Wkt  = (ushort*)(ws + 10 * MiB);
  ushort* Wvt  = (ushort*)(ws + 12 * MiB);
  ushort* Wot  = (ushort*)(ws + 14 * MiB);  // live to end
  float* qkv   = (float*)(ws + 16 * MiB);   // [4096][3072] fp32, dead after conv
  float* qn    = (float*)(ws + 64 * MiB);   // then Qeff in-place
  float* kn    = (float*)(ws + 80 * MiB);   // then Zt in-place
  float* vn    = (float*)(ws + 96 * MiB);   // dead after prep1
  float* beta  = (float*)(ws + 112 * MiB);  // 256 KiB
  float* WbT   = (float*)(ws + 112 * MiB + 256 * 1024);  // 64 KiB
  float* Wkbuf = (float*)(ws + 16 * MiB);   // over qkv (dead after conv)
  float* U0buf = (float*)(ws + 32 * MiB);
  float* Pbuf  = (float*)(ws + 48 * MiB);   // P (prep2abc out, state in)
  float* O0buf = (float*)(ws + 96 * MiB);   // over vn (after prep1)
  float* Sbuf  = (float*)(ws + 16 * MiB);   // over Wkbuf (dead after prep2abc)
  ushort* ob   = (ushort*)(ws + 0);         // over xb (after QKV gemm)

  hipLaunchKernelGGL(cast_kernel, dim3(M_ * D_ / 4 / 256), dim3(256), 0, stream,
                     x, xb, M_ * D_ / 4);
  dim3 tb(32, 8);
  hipLaunchKernelGGL(transpose_cast4_kernel, dim3(32, 32, 4), tb, 0, stream,
                     Wq, Wk, Wv, Wo, Wqt, Wkt, Wvt, Wot);
  hipLaunchKernelGGL(transpose_wb_kernel, dim3(64), dim3(256), 0, stream, Wb, WbT);

  hipLaunchKernelGGL(gemm128_kernel, dim3(M_ / 128, QKVN_ / 128), dim3(256), 0, stream,
                     xb, Wqt, qkv, M_, QKVN_, D_);

  hipLaunchKernelGGL(beta_kernel, dim3(M_ / 16), dim3(256), 0, stream, x, WbT, beta);
  hipLaunchKernelGGL(conv_kernel, dim3(M_), dim3(256), 0, stream,
                     qkv, cq, ck, cv, qn, kn, vn);

  hipLaunchKernelGGL(prep1_kernel, dim3(NCH_), dim3(256), 0, stream,
                     kn, vn, beta, Wkbuf, U0buf);
  hipLaunchKernelGGL(prep2abc_kernel, dim3(NCH_), dim3(256), 0, stream,
                     qn, kn, Wkbuf, U0buf, O0buf, Pbuf);
  hipLaunchKernelGGL(state_kernel, dim3(512), dim3(256), 0, stream,
                     kn, Pbuf, Sbuf);
  hipLaunchKernelGGL(ophase_kernel, dim3(NCH_), dim3(256), 0, stream,
                     qn, Sbuf, O0buf, rg, ob);
  hipLaunchKernelGGL(gemm128_kernel, dim3(M_ / 128, D_ / 128), dim3(256), 0, stream,
                     ob, Wot, out, M_, D_, D_);
}